// Round 1
// 489.903 us; speedup vs baseline: 1.0404x; 1.0404x over previous
//
#include <hip/hip_runtime.h>
#include <stdint.h>

#define N_PROP 100000
#define N_CLS  91
#define NFG    90          // foreground classes
#define TOPK   1000
#define NWORD  16          // 1000 bits -> 16 u64 words
#define CAND_MAX 2048
#define DETS   100
#define CHUNKS 16
#define CHUNK  6250        // N_PROP / CHUNKS
#define SCORE_THRESH 0.05f
#define BBOX_CLIP 4.135166556742356f   // log(1000/16)

__device__ __forceinline__ float clampf(float v, float lo, float hi) {
    return fminf(fmaxf(v, lo), hi);
}

// ---------------------------------------------------------------------------
// Kernel 0: zero two scratch regions
// ---------------------------------------------------------------------------
__global__ __launch_bounds__(256) void zero_kernel(
    unsigned int* __restrict__ p1, int n1,
    unsigned int* __restrict__ p2, int n2) {
    for (int i = blockIdx.x * 256 + threadIdx.x; i < n1; i += gridDim.x * 256)
        p1[i] = 0u;
    for (int i = blockIdx.x * 256 + threadIdx.x; i < n2; i += gridDim.x * 256)
        p2[i] = 0u;
}

// ---------------------------------------------------------------------------
// Kernel 1: softmax over 91 classes, write transposed scores_t[90][N_PROP]
// ---------------------------------------------------------------------------
__global__ __launch_bounds__(256) void softmax_kernel(
    const float* __restrict__ logits, float* __restrict__ scores_t) {
    int row = blockIdx.x * blockDim.x + threadIdx.x;
    if (row >= N_PROP) return;
    const float* lrow = logits + (size_t)row * N_CLS;
    float m = -INFINITY;
    for (int c = 0; c < N_CLS; ++c) m = fmaxf(m, lrow[c]);
    float sum = 0.f;
    for (int c = 0; c < N_CLS; ++c) sum += expf(lrow[c] - m);
    for (int c = 1; c < N_CLS; ++c) {
        float s = expf(lrow[c] - m) / sum;
        scores_t[(size_t)(c - 1) * N_PROP + row] = s;  // coalesced per-c
    }
}

// ---------------------------------------------------------------------------
// Per-class selection (hist1/hist2/compact/sortout) — unchanged from R3.
// ---------------------------------------------------------------------------
__device__ __forceinline__ void suffix_scan_1024(unsigned int* sh, int tid) {
    for (int off = 1; off < 1024; off <<= 1) {
        unsigned int v[4];
#pragma unroll
        for (int q = 0; q < 4; ++q) {
            int x = tid + q * 256;
            v[q] = (x + off < 1024) ? sh[x + off] : 0u;
        }
        __syncthreads();
#pragma unroll
        for (int q = 0; q < 4; ++q) sh[tid + q * 256] += v[q];
        __syncthreads();
    }
}

__global__ __launch_bounds__(256) void hist1_kernel(
    const float* __restrict__ scores_t, unsigned int* __restrict__ ghist1) {
    const int c = blockIdx.x, chunk = blockIdx.y, tid = threadIdx.x;
    __shared__ unsigned int lh[4][1024];
    for (int i = tid; i < 4096; i += 256) (&lh[0][0])[i] = 0u;
    __syncthreads();
    const float* sc = scores_t + (size_t)c * N_PROP + chunk * CHUNK;
    for (int i = tid; i < CHUNK; i += 256) {
        unsigned int bits = __float_as_uint(sc[i]);
        atomicAdd(&lh[tid & 3][bits >> 20], 1u);
    }
    __syncthreads();
    for (int b = tid; b < 1024; b += 256) {
        unsigned int v = lh[0][b] + lh[1][b] + lh[2][b] + lh[3][b];
        if (v) atomicAdd(&ghist1[c * 1024 + b], v);
    }
}

__global__ __launch_bounds__(256) void hist2_kernel(
    const float* __restrict__ scores_t, const unsigned int* __restrict__ ghist1,
    unsigned int* __restrict__ ghist2) {
    const int c = blockIdx.x, chunk = blockIdx.y, tid = threadIdx.x;
    __shared__ unsigned int sh[1024];
    __shared__ unsigned int s_b1;
#pragma unroll
    for (int q = 0; q < 4; ++q) sh[tid + q * 256] = ghist1[c * 1024 + tid + q * 256];
    __syncthreads();
    suffix_scan_1024(sh, tid);
#pragma unroll
    for (int q = 0; q < 4; ++q) {
        int x = tid + q * 256;
        if (sh[x] >= TOPK && (x == 1023 || sh[x + 1] < TOPK)) s_b1 = (unsigned)x;
    }
    __syncthreads();
    const unsigned int b1 = s_b1;
    __syncthreads();
#pragma unroll
    for (int q = 0; q < 4; ++q) sh[tid + q * 256] = 0u;   // reuse as local hist2
    __syncthreads();
    const float* sc = scores_t + (size_t)c * N_PROP + chunk * CHUNK;
    for (int i = tid; i < CHUNK; i += 256) {
        unsigned int bits = __float_as_uint(sc[i]);
        if ((bits >> 20) == b1) atomicAdd(&sh[(bits >> 10) & 1023u], 1u);
    }
    __syncthreads();
    for (int b = tid; b < 1024; b += 256)
        if (sh[b]) atomicAdd(&ghist2[c * 1024 + b], sh[b]);
}

__global__ __launch_bounds__(256) void compact_kernel(
    const float* __restrict__ scores_t, const unsigned int* __restrict__ ghist1,
    const unsigned int* __restrict__ ghist2, unsigned int* __restrict__ gcnt,
    unsigned long long* __restrict__ gcand) {
    const int c = blockIdx.x, chunk = blockIdx.y, tid = threadIdx.x;
    __shared__ unsigned int sh[1024];
    __shared__ unsigned long long stage[CAND_MAX];
    __shared__ unsigned int s_b1, s_above, s_b2, s_lcnt, s_base;
    if (tid == 0) s_lcnt = 0u;
#pragma unroll
    for (int q = 0; q < 4; ++q) sh[tid + q * 256] = ghist1[c * 1024 + tid + q * 256];
    __syncthreads();
    suffix_scan_1024(sh, tid);
#pragma unroll
    for (int q = 0; q < 4; ++q) {
        int x = tid + q * 256;
        if (sh[x] >= TOPK && (x == 1023 || sh[x + 1] < TOPK)) {
            s_b1 = (unsigned)x;
            s_above = (x == 1023) ? 0u : sh[x + 1];
        }
    }
    __syncthreads();
    const unsigned int b1 = s_b1;
    const unsigned int need2 = TOPK - s_above;
    __syncthreads();
#pragma unroll
    for (int q = 0; q < 4; ++q) sh[tid + q * 256] = ghist2[c * 1024 + tid + q * 256];
    __syncthreads();
    suffix_scan_1024(sh, tid);
#pragma unroll
    for (int q = 0; q < 4; ++q) {
        int x = tid + q * 256;
        if (sh[x] >= need2 && (x == 1023 || sh[x + 1] < need2)) s_b2 = (unsigned)x;
    }
    __syncthreads();
    const unsigned int thresh22 = (b1 << 10) | s_b2;
    const float* sc = scores_t + (size_t)c * N_PROP + chunk * CHUNK;
    const int ibase = chunk * CHUNK;
    for (int i = tid; i < CHUNK; i += 256) {
        unsigned int bits = __float_as_uint(sc[i]);
        if ((bits >> 10) >= thresh22) {
            unsigned int pos = atomicAdd(&s_lcnt, 1u);
            if (pos < CAND_MAX)
                stage[pos] = ((unsigned long long)bits << 32) |
                             (unsigned int)(~(unsigned int)(ibase + i));
        }
    }
    __syncthreads();
    unsigned int lcnt = s_lcnt < CAND_MAX ? s_lcnt : CAND_MAX;
    if (tid == 0) s_base = atomicAdd(&gcnt[c], lcnt);  // ONE global atomic
    __syncthreads();
    const unsigned int base = s_base;
    for (unsigned int i = tid; i < lcnt; i += 256) {
        unsigned int pos = base + i;
        if (pos < CAND_MAX) gcand[(size_t)c * CAND_MAX + pos] = stage[i];
    }
}

__global__ __launch_bounds__(1024) void sortout_kernel(
    const unsigned long long* __restrict__ gcand,
    const unsigned int* __restrict__ gcnt,
    float* __restrict__ sel_score, int* __restrict__ sel_idx) {
    const int c = blockIdx.x, tid = threadIdx.x;
    __shared__ unsigned long long cand[CAND_MAX];
    unsigned int cnt = gcnt[c];
    if (cnt > CAND_MAX) cnt = CAND_MAX;
    const unsigned int n = (cnt <= 1024u) ? 1024u : (unsigned)CAND_MAX;
    for (unsigned int i = tid; i < n; i += 1024)
        cand[i] = (i < cnt) ? gcand[(size_t)c * CAND_MAX + i] : 0ull;
    __syncthreads();
    for (unsigned int k = 2; k <= n; k <<= 1) {
        for (unsigned int j = k >> 1; j > 0; j >>= 1) {
            for (unsigned int i = tid; i < n; i += 1024) {
                unsigned int ixj = i ^ j;
                if (ixj > i) {
                    unsigned long long a = cand[i], b = cand[ixj];
                    bool desc = ((i & k) == 0);
                    if (desc ? (a < b) : (a > b)) { cand[i] = b; cand[ixj] = a; }
                }
            }
            __syncthreads();
        }
    }
    if (tid < TOPK) {
        unsigned long long kk = cand[tid];
        sel_score[c * TOPK + tid] = __uint_as_float((unsigned int)(kk >> 32));
        sel_idx[c * TOPK + tid] = (int)(~(unsigned int)(kk & 0xFFFFFFFFull));
    }
}

// ---------------------------------------------------------------------------
// Kernel 3: decode + clip the 90k selected boxes only
// ---------------------------------------------------------------------------
__global__ __launch_bounds__(256) void decode_kernel(
    const float* __restrict__ box_reg, const float* __restrict__ proposals,
    const int* __restrict__ sel_idx, float* __restrict__ sel_box) {
#pragma clang fp contract(off)
    int t = blockIdx.x * blockDim.x + threadIdx.x;
    if (t >= NFG * TOPK) return;
    int c = t / TOPK;           // fg class index, label = c+1
    int i = sel_idx[t];
    float x1 = proposals[i * 4 + 0], y1 = proposals[i * 4 + 1];
    float x2 = proposals[i * 4 + 2], y2 = proposals[i * 4 + 3];
    float w = x2 - x1 + 1.0f, h = y2 - y1 + 1.0f;
    float cx = x1 + 0.5f * w, cy = y1 + 0.5f * h;
    const float* d = box_reg + (size_t)i * (N_CLS * 4) + (size_t)(c + 1) * 4;
    float dx = d[0] / 10.0f, dy = d[1] / 10.0f;
    float dw = fminf(d[2] / 5.0f, BBOX_CLIP);
    float dh = fminf(d[3] / 5.0f, BBOX_CLIP);
    float pcx = dx * w + cx, pcy = dy * h + cy;
    float pw = expf(dw) * w, ph = expf(dh) * h;
    float ox1 = clampf(pcx - 0.5f * pw, 0.f, 1332.f);
    float oy1 = clampf(pcy - 0.5f * ph, 0.f, 799.f);
    float ox2 = clampf(pcx + 0.5f * pw - 1.0f, 0.f, 1332.f);
    float oy2 = clampf(pcy + 0.5f * ph - 1.0f, 0.f, 799.f);
    float4 o = make_float4(ox1, oy1, ox2, oy2);
    ((float4*)sel_box)[t] = o;
}

// ---------------------------------------------------------------------------
// Kernel 4a: suppression bitmask. Grid (class, 4 row-chunks, 4 j-tiles).
// ---------------------------------------------------------------------------
__global__ __launch_bounds__(256) void mask_kernel(
    const float* __restrict__ sel_box, unsigned long long* __restrict__ mask) {
#pragma clang fp contract(off)
    const int c = blockIdx.x;
    const int rbase = blockIdx.y * 256;
    const int jbase0 = blockIdx.z * 256;   // tile of 4 words
    const int r = rbase + threadIdx.x;
    unsigned long long* mrow = mask + ((size_t)c * TOPK + r) * NWORD;
    if (jbase0 + 255 <= rbase) {           // whole tile below diagonal
        if (r < TOPK) {
#pragma unroll
            for (int w4 = 0; w4 < 4; ++w4) mrow[blockIdx.z * 4 + w4] = 0ull;
        }
        return;
    }
    __shared__ float4 box[256];
    {
        int jload = jbase0 + threadIdx.x;
        if (jload < TOPK)
            box[threadIdx.x] = ((const float4*)sel_box)[c * TOPK + jload];
    }
    __syncthreads();
    if (r >= TOPK) return;
    const float4 br = ((const float4*)sel_box)[c * TOPK + r];
    const float ar = (br.z - br.x + 1.0f) * (br.w - br.y + 1.0f);
    for (int w4 = 0; w4 < 4; ++w4) {
        const int wglob = blockIdx.z * 4 + w4;
        const int jbase = wglob * 64;
        if (jbase + 63 <= r) { mrow[wglob] = 0ull; continue; }
        unsigned long long bits = 0ull;
        const int jend = (jbase + 64 < TOPK) ? jbase + 64 : TOPK;
        for (int j = jbase; j < jend; ++j) {
            float4 bj = box[j - jbase0];         // broadcast (uniform addr)
            float aj = (bj.z - bj.x + 1.0f) * (bj.w - bj.y + 1.0f);
            float ltx = fmaxf(br.x, bj.x), lty = fmaxf(br.y, bj.y);
            float rbx = fminf(br.z, bj.z), rby = fminf(br.w, bj.w);
            float iw = fmaxf(rbx - ltx + 1.0f, 0.f);
            float ih = fmaxf(rby - lty + 1.0f, 0.f);
            float inter = iw * ih;
            float uni = ar + aj - inter;
            float diff = (inter + inter) - uni;  // sign always exact
            bool sup;
            if (uni > 0.f && fabsf(diff) > uni * 5e-7f) {
                sup = diff > 0.f;                // fast path (taken ~always)
            } else {
                sup = (inter / uni) > 0.5f;      // exact-window fallback
            }
            if (sup && j > r) bits |= 1ull << (j - jbase);
        }
        mrow[wglob] = bits;
    }
}

// ---------------------------------------------------------------------------
// Kernel 4b: serial greedy sweep, one wave per class. R5 rework:
//   * 4 rows per global load (lane = d*16+w, 512B fully-coalesced), 16
//     statically-indexed prefetch regs -> 64 rows in flight (was 8).
//   * ONE serially-dependent keep-shuffle per 4 rows (was 1 per row); the
//     in-group suppression chain (row i vs rows i+1..i+3) is resolved with
//     wave-uniform 1-bit boolean algebra from keep-independent row shuffles.
//   Bit-exact equivalent of the sequential greedy sweep.
// Still fused with final-topk fpos/fhist1 as in R4.
// ---------------------------------------------------------------------------
__global__ __launch_bounds__(64) void nms_reduce_kernel(
    const unsigned long long* __restrict__ mask, float* __restrict__ sel_score,
    unsigned int* __restrict__ fpos, unsigned int* __restrict__ fhist1) {
    const int c = blockIdx.x;
    const int lane = threadIdx.x;
    const int w = lane & 15;     // word index this lane owns
    const int d = lane >> 4;     // row-in-group slot 0..3
    __shared__ unsigned long long keep_lds[NWORD];
    __shared__ unsigned int lh[1024];

    // init: scores + keep mask. keep word wd replicated in lanes {wd, wd+16,
    // wd+32, wd+48} so "keep &= ~rowword" stays lane-local for every lane.
    float sval[NWORD];
    unsigned long long keep = 0ull;
    for (int wd = 0; wd < NWORD; ++wd) {
        int j = wd * 64 + lane;
        float s = (j < TOPK) ? sel_score[c * TOPK + j] : -1.0f;
        sval[wd] = s;
        unsigned long long m = __ballot(s > SCORE_THRESH);
        if ((lane & 15) == wd) keep = m;
    }

    const unsigned long long* mbase = mask + (size_t)c * TOPK * NWORD;
    // group g = rows 4g..4g+3; lane loads word w of row 4g+d (512B/group).
    unsigned long long pre[16];
#pragma unroll
    for (int p = 0; p < 16; ++p)
        pre[p] = mbase[(size_t)(4 * p + d) * NWORD + w];

    const int NG = TOPK / 4;     // 250 groups, never straddle a 64-bit word
    for (int gb = 0; gb < 256; gb += 16) {
#pragma unroll
        for (int p = 0; p < 16; ++p) {
            const int g = gb + p;
            if (g >= NG) break;                     // uniform
            unsigned long long cur = pre[p];
            {   // prefetch group g+16 into the slot just freed
                const int gn = g + 16;
                pre[p] = (gn < NG) ? mbase[(size_t)(4 * gn + d) * NWORD + w]
                                   : 0ull;
            }
            const int i0 = 4 * g;
            const int kwi = i0 >> 6;                // keep word for this group
            const unsigned int b = (unsigned)i0 & 63u;
            // keep-independent shuffles (pipeline ahead of the serial chain):
            // per-lane row words for the keep update...
            unsigned long long q0 = __shfl(cur, (0 << 4) | w);
            unsigned long long q1 = __shfl(cur, (1 << 4) | w);
            unsigned long long q2 = __shfl(cur, (2 << 4) | w);
            unsigned long long q3 = __shfl(cur, (3 << 4) | w);
            // ...and uniform in-group suppression words (rows 0..2 only)
            unsigned long long r0k = __shfl(cur, (0 << 4) | kwi);
            unsigned long long r1k = __shfl(cur, (1 << 4) | kwi);
            unsigned long long r2k = __shfl(cur, (2 << 4) | kwi);
            // serial dependency: ONE shuffle of keep per 4 rows
            unsigned long long kw = __shfl(keep, kwi);
            const unsigned int k01 = (unsigned)(kw >> b);
            const unsigned int r0s = (unsigned)(r0k >> b);
            const unsigned int r1s = (unsigned)(r1k >> b);
            const unsigned int r2s = (unsigned)(r2k >> b);
            const unsigned int a0 = k01 & 1u;
            const unsigned int a1 = (k01 >> 1) & ~(a0 & (r0s >> 1)) & 1u;
            const unsigned int a2 = (k01 >> 2) & ~(a0 & (r0s >> 2)) &
                                    ~(a1 & (r1s >> 2)) & 1u;
            const unsigned int a3 = (k01 >> 3) & ~(a0 & (r0s >> 3)) &
                                    ~(a1 & (r1s >> 3)) & ~(a2 & (r2s >> 3)) & 1u;
            keep &= ~((q0 & (0ull - (unsigned long long)a0)) |
                      (q1 & (0ull - (unsigned long long)a1)) |
                      (q2 & (0ull - (unsigned long long)a2)) |
                      (q3 & (0ull - (unsigned long long)a3)));
        }
    }

    if (lane < NWORD) keep_lds[lane] = keep;       // d==0 replicas
    for (int b = lane; b < 1024; b += 64) lh[b] = 0u;
    __syncthreads();

    // histogram kept scores (all > SCORE_THRESH > 0 => orderable key = u|sign)
    int mykept = 0;
    for (int ww = 0; ww < NWORD; ++ww) {
        if ((keep_lds[ww] >> lane) & 1ull) {
            unsigned int o = __float_as_uint(sval[ww]) | 0x80000000u;
            atomicAdd(&lh[o >> 22], 1u);
            ++mykept;
        }
    }
#pragma unroll
    for (int off = 32; off > 0; off >>= 1) mykept += __shfl_down(mykept, off);
    if (lane == 0 && mykept) atomicAdd(fpos, (unsigned int)mykept);
    __syncthreads();
    for (int b = lane; b < 1024; b += 64)
        if (lh[b]) atomicAdd(&fhist1[b], lh[b]);

    for (int j = lane; j < TOPK; j += 64) {
        bool k = (keep_lds[j >> 6] >> (j & 63)) & 1ull;
        if (!k) sel_score[c * TOPK + j] = -1.0f;
    }
}

// ---------------------------------------------------------------------------
// Final top-100, parallelized (R4; was one block @106us, occupancy 0.17%).
// Post-NMS values are exactly {score>0.05} U {-1.0}.
//   P >= DETS: two-level histogram select over positives (bit-identical to
//              the reference: -1 entries can never reach the top-100).
//   P <  DETS: compact all positives + first P+DETS flat indices (provably
//              contains the DETS smallest-index -1 entries); sort does the rest.
// ---------------------------------------------------------------------------
__global__ __launch_bounds__(256) void ftk_hist2_kernel(
    const float* __restrict__ sel_score, const unsigned int* __restrict__ fpos,
    const unsigned int* __restrict__ fhist1, unsigned int* __restrict__ fhist2) {
    const int tid = threadIdx.x;
    if (*fpos < DETS) return;
    __shared__ unsigned int sh[1024];
    __shared__ unsigned int s_b1;
#pragma unroll
    for (int q = 0; q < 4; ++q) sh[tid + q * 256] = fhist1[tid + q * 256];
    __syncthreads();
    suffix_scan_1024(sh, tid);
#pragma unroll
    for (int q = 0; q < 4; ++q) {
        int x = tid + q * 256;
        if (sh[x] >= DETS && (x == 1023 || sh[x + 1] < DETS)) s_b1 = (unsigned)x;
    }
    __syncthreads();
    const unsigned int b1 = s_b1;
    __syncthreads();
#pragma unroll
    for (int q = 0; q < 4; ++q) sh[tid + q * 256] = 0u;
    __syncthreads();
    const float* base = sel_score + blockIdx.x * TOPK;
    for (int i = tid; i < TOPK; i += 256) {
        float s = base[i];
        if (!(s > SCORE_THRESH)) continue;
        unsigned int o = __float_as_uint(s) | 0x80000000u;
        if ((o >> 22) == b1) atomicAdd(&sh[(o >> 12) & 1023u], 1u);
    }
    __syncthreads();
    for (int b = tid; b < 1024; b += 256)
        if (sh[b]) atomicAdd(&fhist2[b], sh[b]);
}

__global__ __launch_bounds__(256) void ftk_compact_kernel(
    const float* __restrict__ sel_score, const unsigned int* __restrict__ fpos,
    const unsigned int* __restrict__ fhist1, const unsigned int* __restrict__ fhist2,
    unsigned int* __restrict__ fcnt, unsigned long long* __restrict__ fcand) {
    const int tid = threadIdx.x;
    const unsigned int P = *fpos;
    __shared__ unsigned int sh[1024];
    __shared__ unsigned long long stage[1024];
    __shared__ unsigned int s_b1, s_above, s_b2, s_lcnt, s_base;
    if (tid == 0) s_lcnt = 0u;
    const float* base = sel_score + blockIdx.x * TOPK;
    const int fbase = blockIdx.x * TOPK;
    if (P >= DETS) {
#pragma unroll
        for (int q = 0; q < 4; ++q) sh[tid + q * 256] = fhist1[tid + q * 256];
        __syncthreads();
        suffix_scan_1024(sh, tid);
#pragma unroll
        for (int q = 0; q < 4; ++q) {
            int x = tid + q * 256;
            if (sh[x] >= DETS && (x == 1023 || sh[x + 1] < DETS)) {
                s_b1 = (unsigned)x;
                s_above = (x == 1023) ? 0u : sh[x + 1];
            }
        }
        __syncthreads();
        const unsigned int b1 = s_b1;
        const unsigned int need2 = DETS - s_above;
        __syncthreads();
#pragma unroll
        for (int q = 0; q < 4; ++q) sh[tid + q * 256] = fhist2[tid + q * 256];
        __syncthreads();
        suffix_scan_1024(sh, tid);
#pragma unroll
        for (int q = 0; q < 4; ++q) {
            int x = tid + q * 256;
            if (sh[x] >= need2 && (x == 1023 || sh[x + 1] < need2)) s_b2 = (unsigned)x;
        }
        __syncthreads();
        const unsigned int thresh20 = (s_b1 << 10) | s_b2;
        (void)b1;
        for (int i = tid; i < TOPK; i += 256) {
            float s = base[i];
            if (!(s > SCORE_THRESH)) continue;
            unsigned int o = __float_as_uint(s) | 0x80000000u;
            if ((o >> 12) >= thresh20) {
                unsigned int pos = atomicAdd(&s_lcnt, 1u);
                stage[pos] = ((unsigned long long)o << 32) |
                             (unsigned int)(~(unsigned int)(fbase + i));
            }
        }
    } else {
        for (int i = tid; i < TOPK; i += 256) {
            float s = base[i];
            int flat = fbase + i;
            if ((s > SCORE_THRESH) || flat < (int)(P + DETS)) {
                unsigned int u = __float_as_uint(s);
                unsigned int o = (u & 0x80000000u) ? ~u : (u | 0x80000000u);
                unsigned int pos = atomicAdd(&s_lcnt, 1u);
                stage[pos] = ((unsigned long long)o << 32) |
                             (unsigned int)(~(unsigned int)flat);
            }
        }
    }
    __syncthreads();
    unsigned int lcnt = s_lcnt < 1024u ? s_lcnt : 1024u;
    if (tid == 0) s_base = atomicAdd(fcnt, lcnt);  // ONE global atomic
    __syncthreads();
    const unsigned int bse = s_base;
    for (unsigned int i = tid; i < lcnt; i += 256) {
        unsigned int pos = bse + i;
        if (pos < CAND_MAX) fcand[pos] = stage[i];
    }
}

__global__ __launch_bounds__(1024) void ftk_sort_kernel(
    const unsigned long long* __restrict__ fcand,
    const unsigned int* __restrict__ fcnt,
    const float* __restrict__ sel_score, const float* __restrict__ sel_box,
    float* __restrict__ out) {
    const int tid = threadIdx.x;
    __shared__ unsigned long long cand[CAND_MAX];
    unsigned int cnt = *fcnt;
    if (cnt > CAND_MAX) cnt = CAND_MAX;
    const unsigned int n = (cnt <= 1024u) ? 1024u : (unsigned)CAND_MAX;
    for (unsigned int i = tid; i < n; i += 1024)
        cand[i] = (i < cnt) ? fcand[i] : 0ull;
    __syncthreads();
    for (unsigned int k = 2; k <= n; k <<= 1) {
        for (unsigned int j = k >> 1; j > 0; j >>= 1) {
            for (unsigned int i = tid; i < n; i += 1024) {
                unsigned int ixj = i ^ j;
                if (ixj > i) {
                    unsigned long long a = cand[i], b = cand[ixj];
                    bool desc = ((i & k) == 0);
                    if (desc ? (a < b) : (a > b)) { cand[i] = b; cand[ixj] = a; }
                }
            }
            __syncthreads();
        }
    }
    if (tid < DETS) {
        unsigned long long kk = cand[tid];
        unsigned int flat = ~(unsigned int)(kk & 0xFFFFFFFFull);
        float s = sel_score[flat];
        float4 b = ((const float4*)sel_box)[flat];
        out[tid * 4 + 0] = b.x;
        out[tid * 4 + 1] = b.y;
        out[tid * 4 + 2] = b.z;
        out[tid * 4 + 3] = b.w;
        out[400 + tid] = s;
        out[500 + tid] = (float)(flat / TOPK + 1);   // label
    }
}

// ---------------------------------------------------------------------------
extern "C" void kernel_launch(void* const* d_in, const int* in_sizes, int n_in,
                              void* d_out, int out_size, void* d_ws, size_t ws_size,
                              hipStream_t stream) {
    const float* logits    = (const float*)d_in[0];   // [100000, 91]
    const float* box_reg   = (const float*)d_in[1];   // [100000, 364]
    const float* proposals = (const float*)d_in[2];   // [100000, 4]
    float* out = (float*)d_out;                       // 600 floats

    char* ws = (char*)d_ws;
    size_t off = 0;
    auto walloc = [&](size_t bytes) -> char* {
        char* p = ws + off;
        off += (bytes + 255) & ~(size_t)255;
        return p;
    };
    float* scores_t = (float*)walloc((size_t)NFG * N_PROP * sizeof(float)); // 36 MB
    float* sel_score = (float*)walloc((size_t)NFG * TOPK * sizeof(float));
    int*   sel_idx   = (int*)walloc((size_t)NFG * TOPK * sizeof(int));
    float* sel_box   = (float*)walloc((size_t)NFG * TOPK * 4 * sizeof(float));
    // final-topk scratch (must survive mask writes -> own region)
    unsigned int* fscr = (unsigned int*)walloc((2 + 2048) * sizeof(unsigned int));
    unsigned int* fpos   = fscr;          // [1]
    unsigned int* fcnt   = fscr + 1;      // [1]
    unsigned int* fhist1 = fscr + 2;      // [1024]
    unsigned int* fhist2 = fscr + 2 + 1024; // [1024]
    unsigned long long* fcand =
        (unsigned long long*)walloc(CAND_MAX * sizeof(unsigned long long));
    unsigned long long* mask =
        (unsigned long long*)walloc((size_t)NFG * TOPK * NWORD * 8); // 11.5 MB
    // selection scratch UNIONED with mask region (last read by sortout_kernel,
    // which runs strictly before mask_kernel's first write)
    unsigned int* ghist1 = (unsigned int*)mask;                 // 90*1024
    unsigned int* ghist2 = ghist1 + NFG * 1024;                 // 90*1024
    unsigned int* gcnt   = ghist2 + NFG * 1024;                 // 90
    unsigned long long* gcand =
        (unsigned long long*)(((uintptr_t)(gcnt + NFG) + 255) & ~(uintptr_t)255);
    (void)ws_size; (void)in_sizes; (void)n_in; (void)out_size;

    const int nzero = NFG * 1024 * 2 + NFG;
    zero_kernel<<<64, 256, 0, stream>>>(ghist1, nzero, fscr, 2 + 2048);
    softmax_kernel<<<(N_PROP + 255) / 256, 256, 0, stream>>>(logits, scores_t);
    hist1_kernel<<<dim3(NFG, CHUNKS), 256, 0, stream>>>(scores_t, ghist1);
    hist2_kernel<<<dim3(NFG, CHUNKS), 256, 0, stream>>>(scores_t, ghist1, ghist2);
    compact_kernel<<<dim3(NFG, CHUNKS), 256, 0, stream>>>(scores_t, ghist1, ghist2,
                                                          gcnt, gcand);
    sortout_kernel<<<NFG, 1024, 0, stream>>>(gcand, gcnt, sel_score, sel_idx);
    decode_kernel<<<(NFG * TOPK + 255) / 256, 256, 0, stream>>>(
        box_reg, proposals, sel_idx, sel_box);
    mask_kernel<<<dim3(NFG, 4, 4), 256, 0, stream>>>(sel_box, mask);
    nms_reduce_kernel<<<NFG, 64, 0, stream>>>(mask, sel_score, fpos, fhist1);
    ftk_hist2_kernel<<<NFG, 256, 0, stream>>>(sel_score, fpos, fhist1, fhist2);
    ftk_compact_kernel<<<NFG, 256, 0, stream>>>(sel_score, fpos, fhist1, fhist2,
                                                fcnt, fcand);
    ftk_sort_kernel<<<1, 1024, 0, stream>>>(fcand, fcnt, sel_score, sel_box, out);
}

// Round 2
// 468.947 us; speedup vs baseline: 1.0869x; 1.0447x over previous
//
#include <hip/hip_runtime.h>
#include <stdint.h>

#define N_PROP 100000
#define N_CLS  91
#define NFG    90          // foreground classes
#define TOPK   1000
#define NWORD  16          // 1000 bits -> 16 u64 words
#define CAND_MAX 2048
#define DETS   100
#define CHUNKS 16
#define CHUNK  6250        // N_PROP / CHUNKS
#define SCORE_THRESH 0.05f
#define BBOX_CLIP 4.135166556742356f   // log(1000/16)

__device__ __forceinline__ float clampf(float v, float lo, float hi) {
    return fminf(fmaxf(v, lo), hi);
}

// ---------------------------------------------------------------------------
// Kernel 1: softmax over 91 classes, write transposed scores_t[90][N_PROP].
// R6: also zeroes the selection/final-topk scratch (was a separate launch).
// ---------------------------------------------------------------------------
__global__ __launch_bounds__(256) void softmax_kernel(
    const float* __restrict__ logits, float* __restrict__ scores_t,
    unsigned int* __restrict__ z1, int n1,
    unsigned int* __restrict__ z2, int n2) {
    for (int i = blockIdx.x * 256 + threadIdx.x; i < n1; i += gridDim.x * 256)
        z1[i] = 0u;
    for (int i = blockIdx.x * 256 + threadIdx.x; i < n2; i += gridDim.x * 256)
        z2[i] = 0u;
    int row = blockIdx.x * blockDim.x + threadIdx.x;
    if (row >= N_PROP) return;
    const float* lrow = logits + (size_t)row * N_CLS;
    float m = -INFINITY;
    for (int c = 0; c < N_CLS; ++c) m = fmaxf(m, lrow[c]);
    float sum = 0.f;
    for (int c = 0; c < N_CLS; ++c) sum += expf(lrow[c] - m);
    for (int c = 1; c < N_CLS; ++c) {
        float s = expf(lrow[c] - m) / sum;
        scores_t[(size_t)(c - 1) * N_PROP + row] = s;  // coalesced per-c
    }
}

// ---------------------------------------------------------------------------
// Per-class selection (hist1/hist2/compact/sortout).
// ---------------------------------------------------------------------------
__device__ __forceinline__ void suffix_scan_1024(unsigned int* sh, int tid) {
    for (int off = 1; off < 1024; off <<= 1) {
        unsigned int v[4];
#pragma unroll
        for (int q = 0; q < 4; ++q) {
            int x = tid + q * 256;
            v[q] = (x + off < 1024) ? sh[x + off] : 0u;
        }
        __syncthreads();
#pragma unroll
        for (int q = 0; q < 4; ++q) sh[tid + q * 256] += v[q];
        __syncthreads();
    }
}

__global__ __launch_bounds__(256) void hist1_kernel(
    const float* __restrict__ scores_t, unsigned int* __restrict__ ghist1) {
    const int c = blockIdx.x, chunk = blockIdx.y, tid = threadIdx.x;
    __shared__ unsigned int lh[4][1024];
    for (int i = tid; i < 4096; i += 256) (&lh[0][0])[i] = 0u;
    __syncthreads();
    const float* sc = scores_t + (size_t)c * N_PROP + chunk * CHUNK;
    for (int i = tid; i < CHUNK; i += 256) {
        unsigned int bits = __float_as_uint(sc[i]);
        atomicAdd(&lh[tid & 3][bits >> 20], 1u);
    }
    __syncthreads();
    for (int b = tid; b < 1024; b += 256) {
        unsigned int v = lh[0][b] + lh[1][b] + lh[2][b] + lh[3][b];
        if (v) atomicAdd(&ghist1[c * 1024 + b], v);
    }
}

__global__ __launch_bounds__(256) void hist2_kernel(
    const float* __restrict__ scores_t, const unsigned int* __restrict__ ghist1,
    unsigned int* __restrict__ ghist2) {
    const int c = blockIdx.x, chunk = blockIdx.y, tid = threadIdx.x;
    __shared__ unsigned int sh[1024];
    __shared__ unsigned int s_b1;
#pragma unroll
    for (int q = 0; q < 4; ++q) sh[tid + q * 256] = ghist1[c * 1024 + tid + q * 256];
    __syncthreads();
    suffix_scan_1024(sh, tid);
#pragma unroll
    for (int q = 0; q < 4; ++q) {
        int x = tid + q * 256;
        if (sh[x] >= TOPK && (x == 1023 || sh[x + 1] < TOPK)) s_b1 = (unsigned)x;
    }
    __syncthreads();
    const unsigned int b1 = s_b1;
    __syncthreads();
#pragma unroll
    for (int q = 0; q < 4; ++q) sh[tid + q * 256] = 0u;   // reuse as local hist2
    __syncthreads();
    const float* sc = scores_t + (size_t)c * N_PROP + chunk * CHUNK;
    for (int i = tid; i < CHUNK; i += 256) {
        unsigned int bits = __float_as_uint(sc[i]);
        if ((bits >> 20) == b1) atomicAdd(&sh[(bits >> 10) & 1023u], 1u);
    }
    __syncthreads();
    for (int b = tid; b < 1024; b += 256)
        if (sh[b]) atomicAdd(&ghist2[c * 1024 + b], sh[b]);
}

__global__ __launch_bounds__(256) void compact_kernel(
    const float* __restrict__ scores_t, const unsigned int* __restrict__ ghist1,
    const unsigned int* __restrict__ ghist2, unsigned int* __restrict__ gcnt,
    unsigned long long* __restrict__ gcand) {
    const int c = blockIdx.x, chunk = blockIdx.y, tid = threadIdx.x;
    __shared__ unsigned int sh[1024];
    __shared__ unsigned long long stage[CAND_MAX];
    __shared__ unsigned int s_b1, s_above, s_b2, s_lcnt, s_base;
    if (tid == 0) s_lcnt = 0u;
#pragma unroll
    for (int q = 0; q < 4; ++q) sh[tid + q * 256] = ghist1[c * 1024 + tid + q * 256];
    __syncthreads();
    suffix_scan_1024(sh, tid);
#pragma unroll
    for (int q = 0; q < 4; ++q) {
        int x = tid + q * 256;
        if (sh[x] >= TOPK && (x == 1023 || sh[x + 1] < TOPK)) {
            s_b1 = (unsigned)x;
            s_above = (x == 1023) ? 0u : sh[x + 1];
        }
    }
    __syncthreads();
    const unsigned int b1 = s_b1;
    const unsigned int need2 = TOPK - s_above;
    __syncthreads();
#pragma unroll
    for (int q = 0; q < 4; ++q) sh[tid + q * 256] = ghist2[c * 1024 + tid + q * 256];
    __syncthreads();
    suffix_scan_1024(sh, tid);
#pragma unroll
    for (int q = 0; q < 4; ++q) {
        int x = tid + q * 256;
        if (sh[x] >= need2 && (x == 1023 || sh[x + 1] < need2)) s_b2 = (unsigned)x;
    }
    __syncthreads();
    const unsigned int thresh22 = (b1 << 10) | s_b2;
    const float* sc = scores_t + (size_t)c * N_PROP + chunk * CHUNK;
    const int ibase = chunk * CHUNK;
    for (int i = tid; i < CHUNK; i += 256) {
        unsigned int bits = __float_as_uint(sc[i]);
        if ((bits >> 10) >= thresh22) {
            unsigned int pos = atomicAdd(&s_lcnt, 1u);
            if (pos < CAND_MAX)
                stage[pos] = ((unsigned long long)bits << 32) |
                             (unsigned int)(~(unsigned int)(ibase + i));
        }
    }
    __syncthreads();
    unsigned int lcnt = s_lcnt < CAND_MAX ? s_lcnt : CAND_MAX;
    if (tid == 0) s_base = atomicAdd(&gcnt[c], lcnt);  // ONE global atomic
    __syncthreads();
    const unsigned int base = s_base;
    for (unsigned int i = tid; i < lcnt; i += 256) {
        unsigned int pos = base + i;
        if (pos < CAND_MAX) gcand[(size_t)c * CAND_MAX + pos] = stage[i];
    }
}

// ---------------------------------------------------------------------------
// Kernel 2b: per-class sort of candidates + fused box decode (R6: decode was
// its own kernel; the selected indices are already in LDS here, so decode
// inline and drop the sel_idx global round-trip + one launch).
// ---------------------------------------------------------------------------
__global__ __launch_bounds__(1024) void sortout_kernel(
    const unsigned long long* __restrict__ gcand,
    const unsigned int* __restrict__ gcnt,
    const float* __restrict__ box_reg, const float* __restrict__ proposals,
    float* __restrict__ sel_score, float* __restrict__ sel_box) {
#pragma clang fp contract(off)
    const int c = blockIdx.x, tid = threadIdx.x;
    __shared__ unsigned long long cand[CAND_MAX];
    unsigned int cnt = gcnt[c];
    if (cnt > CAND_MAX) cnt = CAND_MAX;
    const unsigned int n = (cnt <= 1024u) ? 1024u : (unsigned)CAND_MAX;
    for (unsigned int i = tid; i < n; i += 1024)
        cand[i] = (i < cnt) ? gcand[(size_t)c * CAND_MAX + i] : 0ull;
    __syncthreads();
    for (unsigned int k = 2; k <= n; k <<= 1) {
        for (unsigned int j = k >> 1; j > 0; j >>= 1) {
            for (unsigned int i = tid; i < n; i += 1024) {
                unsigned int ixj = i ^ j;
                if (ixj > i) {
                    unsigned long long a = cand[i], b = cand[ixj];
                    bool desc = ((i & k) == 0);
                    if (desc ? (a < b) : (a > b)) { cand[i] = b; cand[ixj] = a; }
                }
            }
            __syncthreads();
        }
    }
    if (tid < TOPK) {
        unsigned long long kk = cand[tid];
        sel_score[c * TOPK + tid] = __uint_as_float((unsigned int)(kk >> 32));
        const int i = (int)(~(unsigned int)(kk & 0xFFFFFFFFull));
        // ---- inline decode + clip (bit-identical to previous decode_kernel)
        float x1 = proposals[i * 4 + 0], y1 = proposals[i * 4 + 1];
        float x2 = proposals[i * 4 + 2], y2 = proposals[i * 4 + 3];
        float w = x2 - x1 + 1.0f, h = y2 - y1 + 1.0f;
        float cx = x1 + 0.5f * w, cy = y1 + 0.5f * h;
        const float* d = box_reg + (size_t)i * (N_CLS * 4) + (size_t)(c + 1) * 4;
        float dx = d[0] / 10.0f, dy = d[1] / 10.0f;
        float dw = fminf(d[2] / 5.0f, BBOX_CLIP);
        float dh = fminf(d[3] / 5.0f, BBOX_CLIP);
        float pcx = dx * w + cx, pcy = dy * h + cy;
        float pw = expf(dw) * w, ph = expf(dh) * h;
        float ox1 = clampf(pcx - 0.5f * pw, 0.f, 1332.f);
        float oy1 = clampf(pcy - 0.5f * ph, 0.f, 799.f);
        float ox2 = clampf(pcx + 0.5f * pw - 1.0f, 0.f, 1332.f);
        float oy2 = clampf(pcy + 0.5f * ph - 1.0f, 0.f, 799.f);
        ((float4*)sel_box)[c * TOPK + tid] = make_float4(ox1, oy1, ox2, oy2);
    }
}

// ---------------------------------------------------------------------------
// Kernel 4a: suppression bitmask. Grid (class, 4 row-chunks, 4 j-tiles).
// R6: per-j areas precomputed into LDS (uniform-j broadcast read).
// ---------------------------------------------------------------------------
__global__ __launch_bounds__(256) void mask_kernel(
    const float* __restrict__ sel_box, unsigned long long* __restrict__ mask) {
#pragma clang fp contract(off)
    const int c = blockIdx.x;
    const int rbase = blockIdx.y * 256;
    const int jbase0 = blockIdx.z * 256;   // tile of 4 words
    const int r = rbase + threadIdx.x;
    unsigned long long* mrow = mask + ((size_t)c * TOPK + r) * NWORD;
    if (jbase0 + 255 <= rbase) {           // whole tile below diagonal
        if (r < TOPK) {
#pragma unroll
            for (int w4 = 0; w4 < 4; ++w4) mrow[blockIdx.z * 4 + w4] = 0ull;
        }
        return;
    }
    __shared__ float4 box[256];
    __shared__ float sarea[256];
    {
        int jload = jbase0 + threadIdx.x;
        if (jload < TOPK) {
            float4 b4 = ((const float4*)sel_box)[c * TOPK + jload];
            box[threadIdx.x] = b4;
            sarea[threadIdx.x] = (b4.z - b4.x + 1.0f) * (b4.w - b4.y + 1.0f);
        }
    }
    __syncthreads();
    if (r >= TOPK) return;
    const float4 br = ((const float4*)sel_box)[c * TOPK + r];
    const float ar = (br.z - br.x + 1.0f) * (br.w - br.y + 1.0f);
    for (int w4 = 0; w4 < 4; ++w4) {
        const int wglob = blockIdx.z * 4 + w4;
        const int jbase = wglob * 64;
        if (jbase + 63 <= r) { mrow[wglob] = 0ull; continue; }
        unsigned long long bits = 0ull;
        const int jend = (jbase + 64 < TOPK) ? jbase + 64 : TOPK;
        for (int j = jbase; j < jend; ++j) {
            float4 bj = box[j - jbase0];         // broadcast (uniform addr)
            float aj = sarea[j - jbase0];
            float ltx = fmaxf(br.x, bj.x), lty = fmaxf(br.y, bj.y);
            float rbx = fminf(br.z, bj.z), rby = fminf(br.w, bj.w);
            float iw = fmaxf(rbx - ltx + 1.0f, 0.f);
            float ih = fmaxf(rby - lty + 1.0f, 0.f);
            float inter = iw * ih;
            float uni = ar + aj - inter;
            float diff = (inter + inter) - uni;  // sign always exact
            bool sup;
            if (uni > 0.f && fabsf(diff) > uni * 5e-7f) {
                sup = diff > 0.f;                // fast path (taken ~always)
            } else {
                sup = (inter / uni) > 0.5f;      // exact-window fallback
            }
            if (sup && j > r) bits |= 1ull << (j - jbase);
        }
        mrow[wglob] = bits;
    }
}

// ---------------------------------------------------------------------------
// Kernel 4b: serial greedy sweep. R6 rework: 256 threads/class; 4 waves
// cooperatively stage the whole 128 KB mask into LDS (gfx950: 160 KB/WG),
// then wave 0 runs the bit-exact boolean-algebra sweep entirely from LDS --
// the 250-step serial chain never touches global-memory latency again.
// Still fused with final-topk fpos/fhist1.
// ---------------------------------------------------------------------------
__global__ __launch_bounds__(256) void nms_reduce_kernel(
    const unsigned long long* __restrict__ mask, float* __restrict__ sel_score,
    unsigned int* __restrict__ fpos, unsigned int* __restrict__ fhist1) {
    const int c = blockIdx.x;
    const int tid = threadIdx.x;
    const int lane = tid & 63;
    const int wv = tid >> 6;
    __shared__ __align__(16) unsigned long long smask[TOPK * NWORD]; // 125 KiB
    __shared__ unsigned long long keep_lds[NWORD];
    __shared__ unsigned int lh[1024];

    const unsigned long long* mbase = mask + (size_t)c * TOPK * NWORD;

    // wave 0: scores + initial keep ballot (replicated across 16-lane groups)
    float sval[NWORD];
    unsigned long long keep = 0ull;
    if (wv == 0) {
        for (int wd = 0; wd < NWORD; ++wd) {
            int j = wd * 64 + lane;
            float s = (j < TOPK) ? sel_score[c * TOPK + j] : -1.0f;
            sval[wd] = s;
            unsigned long long m = __ballot(s > SCORE_THRESH);
            if ((lane & 15) == wd) keep = m;
        }
    }
    // all 256 threads: stage mask -> LDS, 16 B/lane fully coalesced
    {
        ulonglong2* s2 = (ulonglong2*)smask;
        const ulonglong2* g2 = (const ulonglong2*)mbase;
        for (int i = tid; i < TOPK * NWORD / 2; i += 256) s2[i] = g2[i];
    }
    __syncthreads();

    if (wv == 0) {
        const int w = lane & 15;     // word index this lane owns
        const int d = lane >> 4;     // row-in-group slot 0..3
        const int NG = TOPK / 4;     // 250 groups
        unsigned long long p0 = smask[(size_t)(0 + d) * NWORD + w];
        unsigned long long p1 = smask[(size_t)(4 + d) * NWORD + w];
        for (int g = 0; g < NG; ++g) {
            unsigned long long cur = p0;
            p0 = p1;
            p1 = (g + 2 < NG) ? smask[(size_t)(4 * (g + 2) + d) * NWORD + w]
                              : 0ull;
            const int i0 = 4 * g;
            const int kwi = i0 >> 6;                // keep word for this group
            const unsigned int b = (unsigned)i0 & 63u;
            // keep-independent shuffles (pipeline ahead of the serial chain)
            unsigned long long q0 = __shfl(cur, (0 << 4) | w);
            unsigned long long q1 = __shfl(cur, (1 << 4) | w);
            unsigned long long q2 = __shfl(cur, (2 << 4) | w);
            unsigned long long q3 = __shfl(cur, (3 << 4) | w);
            unsigned long long r0k = __shfl(cur, (0 << 4) | kwi);
            unsigned long long r1k = __shfl(cur, (1 << 4) | kwi);
            unsigned long long r2k = __shfl(cur, (2 << 4) | kwi);
            // serial dependency: ONE shuffle of keep per 4 rows
            unsigned long long kw = __shfl(keep, kwi);
            const unsigned int k01 = (unsigned)(kw >> b);
            const unsigned int r0s = (unsigned)(r0k >> b);
            const unsigned int r1s = (unsigned)(r1k >> b);
            const unsigned int r2s = (unsigned)(r2k >> b);
            const unsigned int a0 = k01 & 1u;
            const unsigned int a1 = (k01 >> 1) & ~(a0 & (r0s >> 1)) & 1u;
            const unsigned int a2 = (k01 >> 2) & ~(a0 & (r0s >> 2)) &
                                    ~(a1 & (r1s >> 2)) & 1u;
            const unsigned int a3 = (k01 >> 3) & ~(a0 & (r0s >> 3)) &
                                    ~(a1 & (r1s >> 3)) & ~(a2 & (r2s >> 3)) & 1u;
            keep &= ~((q0 & (0ull - (unsigned long long)a0)) |
                      (q1 & (0ull - (unsigned long long)a1)) |
                      (q2 & (0ull - (unsigned long long)a2)) |
                      (q3 & (0ull - (unsigned long long)a3)));
        }
        if (lane < NWORD) keep_lds[lane] = keep;   // d==0 replicas
    } else {
        for (int b = tid - 64; b < 1024; b += 192) lh[b] = 0u;
    }
    __syncthreads();

    // wave 0: histogram kept scores (all > SCORE_THRESH > 0 => key = u|sign)
    if (wv == 0) {
        int mykept = 0;
        for (int ww = 0; ww < NWORD; ++ww) {
            if ((keep_lds[ww] >> lane) & 1ull) {
                unsigned int o = __float_as_uint(sval[ww]) | 0x80000000u;
                atomicAdd(&lh[o >> 22], 1u);
                ++mykept;
            }
        }
#pragma unroll
        for (int off = 32; off > 0; off >>= 1) mykept += __shfl_down(mykept, off);
        if (lane == 0 && mykept) atomicAdd(fpos, (unsigned int)mykept);
    }
    __syncthreads();

    for (int b = tid; b < 1024; b += 256)
        if (lh[b]) atomicAdd(&fhist1[b], lh[b]);
    for (int j = tid; j < TOPK; j += 256) {
        bool k = (keep_lds[j >> 6] >> (j & 63)) & 1ull;
        if (!k) sel_score[c * TOPK + j] = -1.0f;
    }
}

// ---------------------------------------------------------------------------
// Final top-100, parallelized. Post-NMS values are exactly {score>0.05} U {-1}.
// ---------------------------------------------------------------------------
__global__ __launch_bounds__(256) void ftk_hist2_kernel(
    const float* __restrict__ sel_score, const unsigned int* __restrict__ fpos,
    const unsigned int* __restrict__ fhist1, unsigned int* __restrict__ fhist2) {
    const int tid = threadIdx.x;
    if (*fpos < DETS) return;
    __shared__ unsigned int sh[1024];
    __shared__ unsigned int s_b1;
#pragma unroll
    for (int q = 0; q < 4; ++q) sh[tid + q * 256] = fhist1[tid + q * 256];
    __syncthreads();
    suffix_scan_1024(sh, tid);
#pragma unroll
    for (int q = 0; q < 4; ++q) {
        int x = tid + q * 256;
        if (sh[x] >= DETS && (x == 1023 || sh[x + 1] < DETS)) s_b1 = (unsigned)x;
    }
    __syncthreads();
    const unsigned int b1 = s_b1;
    __syncthreads();
#pragma unroll
    for (int q = 0; q < 4; ++q) sh[tid + q * 256] = 0u;
    __syncthreads();
    const float* base = sel_score + blockIdx.x * TOPK;
    for (int i = tid; i < TOPK; i += 256) {
        float s = base[i];
        if (!(s > SCORE_THRESH)) continue;
        unsigned int o = __float_as_uint(s) | 0x80000000u;
        if ((o >> 22) == b1) atomicAdd(&sh[(o >> 12) & 1023u], 1u);
    }
    __syncthreads();
    for (int b = tid; b < 1024; b += 256)
        if (sh[b]) atomicAdd(&fhist2[b], sh[b]);
}

__global__ __launch_bounds__(256) void ftk_compact_kernel(
    const float* __restrict__ sel_score, const unsigned int* __restrict__ fpos,
    const unsigned int* __restrict__ fhist1, const unsigned int* __restrict__ fhist2,
    unsigned int* __restrict__ fcnt, unsigned long long* __restrict__ fcand) {
    const int tid = threadIdx.x;
    const unsigned int P = *fpos;
    __shared__ unsigned int sh[1024];
    __shared__ unsigned long long stage[1024];
    __shared__ unsigned int s_b1, s_above, s_b2, s_lcnt, s_base;
    if (tid == 0) s_lcnt = 0u;
    const float* base = sel_score + blockIdx.x * TOPK;
    const int fbase = blockIdx.x * TOPK;
    if (P >= DETS) {
#pragma unroll
        for (int q = 0; q < 4; ++q) sh[tid + q * 256] = fhist1[tid + q * 256];
        __syncthreads();
        suffix_scan_1024(sh, tid);
#pragma unroll
        for (int q = 0; q < 4; ++q) {
            int x = tid + q * 256;
            if (sh[x] >= DETS && (x == 1023 || sh[x + 1] < DETS)) {
                s_b1 = (unsigned)x;
                s_above = (x == 1023) ? 0u : sh[x + 1];
            }
        }
        __syncthreads();
        const unsigned int b1 = s_b1;
        const unsigned int need2 = DETS - s_above;
        __syncthreads();
#pragma unroll
        for (int q = 0; q < 4; ++q) sh[tid + q * 256] = fhist2[tid + q * 256];
        __syncthreads();
        suffix_scan_1024(sh, tid);
#pragma unroll
        for (int q = 0; q < 4; ++q) {
            int x = tid + q * 256;
            if (sh[x] >= need2 && (x == 1023 || sh[x + 1] < need2)) s_b2 = (unsigned)x;
        }
        __syncthreads();
        const unsigned int thresh20 = (s_b1 << 10) | s_b2;
        (void)b1;
        for (int i = tid; i < TOPK; i += 256) {
            float s = base[i];
            if (!(s > SCORE_THRESH)) continue;
            unsigned int o = __float_as_uint(s) | 0x80000000u;
            if ((o >> 12) >= thresh20) {
                unsigned int pos = atomicAdd(&s_lcnt, 1u);
                stage[pos] = ((unsigned long long)o << 32) |
                             (unsigned int)(~(unsigned int)(fbase + i));
            }
        }
    } else {
        for (int i = tid; i < TOPK; i += 256) {
            float s = base[i];
            int flat = fbase + i;
            if ((s > SCORE_THRESH) || flat < (int)(P + DETS)) {
                unsigned int u = __float_as_uint(s);
                unsigned int o = (u & 0x80000000u) ? ~u : (u | 0x80000000u);
                unsigned int pos = atomicAdd(&s_lcnt, 1u);
                stage[pos] = ((unsigned long long)o << 32) |
                             (unsigned int)(~(unsigned int)flat);
            }
        }
    }
    __syncthreads();
    unsigned int lcnt = s_lcnt < 1024u ? s_lcnt : 1024u;
    if (tid == 0) s_base = atomicAdd(fcnt, lcnt);  // ONE global atomic
    __syncthreads();
    const unsigned int bse = s_base;
    for (unsigned int i = tid; i < lcnt; i += 256) {
        unsigned int pos = bse + i;
        if (pos < CAND_MAX) fcand[pos] = stage[i];
    }
}

__global__ __launch_bounds__(1024) void ftk_sort_kernel(
    const unsigned long long* __restrict__ fcand,
    const unsigned int* __restrict__ fcnt,
    const float* __restrict__ sel_score, const float* __restrict__ sel_box,
    float* __restrict__ out) {
    const int tid = threadIdx.x;
    __shared__ unsigned long long cand[CAND_MAX];
    unsigned int cnt = *fcnt;
    if (cnt > CAND_MAX) cnt = CAND_MAX;
    const unsigned int n = (cnt <= 1024u) ? 1024u : (unsigned)CAND_MAX;
    for (unsigned int i = tid; i < n; i += 1024)
        cand[i] = (i < cnt) ? fcand[i] : 0ull;
    __syncthreads();
    for (unsigned int k = 2; k <= n; k <<= 1) {
        for (unsigned int j = k >> 1; j > 0; j >>= 1) {
            for (unsigned int i = tid; i < n; i += 1024) {
                unsigned int ixj = i ^ j;
                if (ixj > i) {
                    unsigned long long a = cand[i], b = cand[ixj];
                    bool desc = ((i & k) == 0);
                    if (desc ? (a < b) : (a > b)) { cand[i] = b; cand[ixj] = a; }
                }
            }
            __syncthreads();
        }
    }
    if (tid < DETS) {
        unsigned long long kk = cand[tid];
        unsigned int flat = ~(unsigned int)(kk & 0xFFFFFFFFull);
        float s = sel_score[flat];
        float4 b = ((const float4*)sel_box)[flat];
        out[tid * 4 + 0] = b.x;
        out[tid * 4 + 1] = b.y;
        out[tid * 4 + 2] = b.z;
        out[tid * 4 + 3] = b.w;
        out[400 + tid] = s;
        out[500 + tid] = (float)(flat / TOPK + 1);   // label
    }
}

// ---------------------------------------------------------------------------
extern "C" void kernel_launch(void* const* d_in, const int* in_sizes, int n_in,
                              void* d_out, int out_size, void* d_ws, size_t ws_size,
                              hipStream_t stream) {
    const float* logits    = (const float*)d_in[0];   // [100000, 91]
    const float* box_reg   = (const float*)d_in[1];   // [100000, 364]
    const float* proposals = (const float*)d_in[2];   // [100000, 4]
    float* out = (float*)d_out;                       // 600 floats

    char* ws = (char*)d_ws;
    size_t off = 0;
    auto walloc = [&](size_t bytes) -> char* {
        char* p = ws + off;
        off += (bytes + 255) & ~(size_t)255;
        return p;
    };
    float* scores_t = (float*)walloc((size_t)NFG * N_PROP * sizeof(float)); // 36 MB
    float* sel_score = (float*)walloc((size_t)NFG * TOPK * sizeof(float));
    float* sel_box   = (float*)walloc((size_t)NFG * TOPK * 4 * sizeof(float));
    // final-topk scratch (must survive mask writes -> own region)
    unsigned int* fscr = (unsigned int*)walloc((2 + 2048) * sizeof(unsigned int));
    unsigned int* fpos   = fscr;          // [1]
    unsigned int* fcnt   = fscr + 1;      // [1]
    unsigned int* fhist1 = fscr + 2;      // [1024]
    unsigned int* fhist2 = fscr + 2 + 1024; // [1024]
    unsigned long long* fcand =
        (unsigned long long*)walloc(CAND_MAX * sizeof(unsigned long long));
    unsigned long long* mask =
        (unsigned long long*)walloc((size_t)NFG * TOPK * NWORD * 8); // 11.5 MB
    // selection scratch UNIONED with mask region (last read by sortout_kernel,
    // which runs strictly before mask_kernel's first write)
    unsigned int* ghist1 = (unsigned int*)mask;                 // 90*1024
    unsigned int* ghist2 = ghist1 + NFG * 1024;                 // 90*1024
    unsigned int* gcnt   = ghist2 + NFG * 1024;                 // 90
    unsigned long long* gcand =
        (unsigned long long*)(((uintptr_t)(gcnt + NFG) + 255) & ~(uintptr_t)255);
    (void)ws_size; (void)in_sizes; (void)n_in; (void)out_size;

    const int nzero = NFG * 1024 * 2 + NFG;
    softmax_kernel<<<(N_PROP + 255) / 256, 256, 0, stream>>>(
        logits, scores_t, ghist1, nzero, fscr, 2 + 2048);
    hist1_kernel<<<dim3(NFG, CHUNKS), 256, 0, stream>>>(scores_t, ghist1);
    hist2_kernel<<<dim3(NFG, CHUNKS), 256, 0, stream>>>(scores_t, ghist1, ghist2);
    compact_kernel<<<dim3(NFG, CHUNKS), 256, 0, stream>>>(scores_t, ghist1, ghist2,
                                                          gcnt, gcand);
    sortout_kernel<<<NFG, 1024, 0, stream>>>(gcand, gcnt, box_reg, proposals,
                                             sel_score, sel_box);
    mask_kernel<<<dim3(NFG, 4, 4), 256, 0, stream>>>(sel_box, mask);
    nms_reduce_kernel<<<NFG, 256, 0, stream>>>(mask, sel_score, fpos, fhist1);
    ftk_hist2_kernel<<<NFG, 256, 0, stream>>>(sel_score, fpos, fhist1, fhist2);
    ftk_compact_kernel<<<NFG, 256, 0, stream>>>(sel_score, fpos, fhist1, fhist2,
                                                fcnt, fcand);
    ftk_sort_kernel<<<1, 1024, 0, stream>>>(fcand, fcnt, sel_score, sel_box, out);
}

// Round 6
// 468.202 us; speedup vs baseline: 1.0886x; 1.0016x over previous
//
#include <hip/hip_runtime.h>
#include <stdint.h>

#define N_PROP 100000
#define N_CLS  91
#define NFG    90          // foreground classes
#define TOPK   1000
#define NWORD  16          // 1000 bits -> 16 u64 words
#define CAND_MAX 2048
#define DETS   100
#define CHUNKS 16
#define CHUNK  6250        // N_PROP / CHUNKS
#define SCORE_THRESH 0.05f
#define BBOX_CLIP 4.135166556742356f   // log(1000/16)

__device__ __forceinline__ float clampf(float v, float lo, float hi) {
    return fminf(fmaxf(v, lo), hi);
}

// ---------------------------------------------------------------------------
// Kernel 1: softmax over 91 classes, write transposed scores_t[90][N_PROP].
// Also zeroes the selection/final-topk scratch (was a separate launch).
// ---------------------------------------------------------------------------
__global__ __launch_bounds__(256) void softmax_kernel(
    const float* __restrict__ logits, float* __restrict__ scores_t,
    unsigned int* __restrict__ z1, int n1,
    unsigned int* __restrict__ z2, int n2) {
    for (int i = blockIdx.x * 256 + threadIdx.x; i < n1; i += gridDim.x * 256)
        z1[i] = 0u;
    for (int i = blockIdx.x * 256 + threadIdx.x; i < n2; i += gridDim.x * 256)
        z2[i] = 0u;
    int row = blockIdx.x * blockDim.x + threadIdx.x;
    if (row >= N_PROP) return;
    const float* lrow = logits + (size_t)row * N_CLS;
    float m = -INFINITY;
    for (int c = 0; c < N_CLS; ++c) m = fmaxf(m, lrow[c]);
    float sum = 0.f;
    for (int c = 0; c < N_CLS; ++c) sum += expf(lrow[c] - m);
    for (int c = 1; c < N_CLS; ++c) {
        float s = expf(lrow[c] - m) / sum;
        scores_t[(size_t)(c - 1) * N_PROP + row] = s;  // coalesced per-c
    }
}

// ---------------------------------------------------------------------------
// Per-class selection (hist1/hist2/compact/sortout).
// ---------------------------------------------------------------------------
__device__ __forceinline__ void suffix_scan_1024(unsigned int* sh, int tid) {
    for (int off = 1; off < 1024; off <<= 1) {
        unsigned int v[4];
#pragma unroll
        for (int q = 0; q < 4; ++q) {
            int x = tid + q * 256;
            v[q] = (x + off < 1024) ? sh[x + off] : 0u;
        }
        __syncthreads();
#pragma unroll
        for (int q = 0; q < 4; ++q) sh[tid + q * 256] += v[q];
        __syncthreads();
    }
}

__global__ __launch_bounds__(256) void hist1_kernel(
    const float* __restrict__ scores_t, unsigned int* __restrict__ ghist1) {
    const int c = blockIdx.x, chunk = blockIdx.y, tid = threadIdx.x;
    __shared__ unsigned int lh[4][1024];
    for (int i = tid; i < 4096; i += 256) (&lh[0][0])[i] = 0u;
    __syncthreads();
    const float* sc = scores_t + (size_t)c * N_PROP + chunk * CHUNK;
    for (int i = tid; i < CHUNK; i += 256) {
        unsigned int bits = __float_as_uint(sc[i]);
        atomicAdd(&lh[tid & 3][bits >> 20], 1u);
    }
    __syncthreads();
    for (int b = tid; b < 1024; b += 256) {
        unsigned int v = lh[0][b] + lh[1][b] + lh[2][b] + lh[3][b];
        if (v) atomicAdd(&ghist1[c * 1024 + b], v);
    }
}

__global__ __launch_bounds__(256) void hist2_kernel(
    const float* __restrict__ scores_t, const unsigned int* __restrict__ ghist1,
    unsigned int* __restrict__ ghist2) {
    const int c = blockIdx.x, chunk = blockIdx.y, tid = threadIdx.x;
    __shared__ unsigned int sh[1024];
    __shared__ unsigned int s_b1;
#pragma unroll
    for (int q = 0; q < 4; ++q) sh[tid + q * 256] = ghist1[c * 1024 + tid + q * 256];
    __syncthreads();
    suffix_scan_1024(sh, tid);
#pragma unroll
    for (int q = 0; q < 4; ++q) {
        int x = tid + q * 256;
        if (sh[x] >= TOPK && (x == 1023 || sh[x + 1] < TOPK)) s_b1 = (unsigned)x;
    }
    __syncthreads();
    const unsigned int b1 = s_b1;
    __syncthreads();
#pragma unroll
    for (int q = 0; q < 4; ++q) sh[tid + q * 256] = 0u;   // reuse as local hist2
    __syncthreads();
    const float* sc = scores_t + (size_t)c * N_PROP + chunk * CHUNK;
    for (int i = tid; i < CHUNK; i += 256) {
        unsigned int bits = __float_as_uint(sc[i]);
        if ((bits >> 20) == b1) atomicAdd(&sh[(bits >> 10) & 1023u], 1u);
    }
    __syncthreads();
    for (int b = tid; b < 1024; b += 256)
        if (sh[b]) atomicAdd(&ghist2[c * 1024 + b], sh[b]);
}

__global__ __launch_bounds__(256) void compact_kernel(
    const float* __restrict__ scores_t, const unsigned int* __restrict__ ghist1,
    const unsigned int* __restrict__ ghist2, unsigned int* __restrict__ gcnt,
    unsigned long long* __restrict__ gcand) {
    const int c = blockIdx.x, chunk = blockIdx.y, tid = threadIdx.x;
    __shared__ unsigned int sh[1024];
    __shared__ unsigned long long stage[CAND_MAX];
    __shared__ unsigned int s_b1, s_above, s_b2, s_lcnt, s_base;
    if (tid == 0) s_lcnt = 0u;
#pragma unroll
    for (int q = 0; q < 4; ++q) sh[tid + q * 256] = ghist1[c * 1024 + tid + q * 256];
    __syncthreads();
    suffix_scan_1024(sh, tid);
#pragma unroll
    for (int q = 0; q < 4; ++q) {
        int x = tid + q * 256;
        if (sh[x] >= TOPK && (x == 1023 || sh[x + 1] < TOPK)) {
            s_b1 = (unsigned)x;
            s_above = (x == 1023) ? 0u : sh[x + 1];
        }
    }
    __syncthreads();
    const unsigned int b1 = s_b1;
    const unsigned int need2 = TOPK - s_above;
    __syncthreads();
#pragma unroll
    for (int q = 0; q < 4; ++q) sh[tid + q * 256] = ghist2[c * 1024 + tid + q * 256];
    __syncthreads();
    suffix_scan_1024(sh, tid);
#pragma unroll
    for (int q = 0; q < 4; ++q) {
        int x = tid + q * 256;
        if (sh[x] >= need2 && (x == 1023 || sh[x + 1] < need2)) s_b2 = (unsigned)x;
    }
    __syncthreads();
    const unsigned int thresh22 = (b1 << 10) | s_b2;
    const float* sc = scores_t + (size_t)c * N_PROP + chunk * CHUNK;
    const int ibase = chunk * CHUNK;
    for (int i = tid; i < CHUNK; i += 256) {
        unsigned int bits = __float_as_uint(sc[i]);
        if ((bits >> 10) >= thresh22) {
            unsigned int pos = atomicAdd(&s_lcnt, 1u);
            if (pos < CAND_MAX)
                stage[pos] = ((unsigned long long)bits << 32) |
                             (unsigned int)(~(unsigned int)(ibase + i));
        }
    }
    __syncthreads();
    unsigned int lcnt = s_lcnt < CAND_MAX ? s_lcnt : CAND_MAX;
    if (tid == 0) s_base = atomicAdd(&gcnt[c], lcnt);  // ONE global atomic
    __syncthreads();
    const unsigned int base = s_base;
    for (unsigned int i = tid; i < lcnt; i += 256) {
        unsigned int pos = base + i;
        if (pos < CAND_MAX) gcand[(size_t)c * CAND_MAX + pos] = stage[i];
    }
}

// ---------------------------------------------------------------------------
// Kernel 2b: per-class sort of candidates + fused box decode (the selected
// indices are already in LDS here, so decode inline; drops the sel_idx
// global round-trip + one launch).
// ---------------------------------------------------------------------------
__global__ __launch_bounds__(1024) void sortout_kernel(
    const unsigned long long* __restrict__ gcand,
    const unsigned int* __restrict__ gcnt,
    const float* __restrict__ box_reg, const float* __restrict__ proposals,
    float* __restrict__ sel_score, float* __restrict__ sel_box) {
#pragma clang fp contract(off)
    const int c = blockIdx.x, tid = threadIdx.x;
    __shared__ unsigned long long cand[CAND_MAX];
    unsigned int cnt = gcnt[c];
    if (cnt > CAND_MAX) cnt = CAND_MAX;
    const unsigned int n = (cnt <= 1024u) ? 1024u : (unsigned)CAND_MAX;
    for (unsigned int i = tid; i < n; i += 1024)
        cand[i] = (i < cnt) ? gcand[(size_t)c * CAND_MAX + i] : 0ull;
    __syncthreads();
    for (unsigned int k = 2; k <= n; k <<= 1) {
        for (unsigned int j = k >> 1; j > 0; j >>= 1) {
            for (unsigned int i = tid; i < n; i += 1024) {
                unsigned int ixj = i ^ j;
                if (ixj > i) {
                    unsigned long long a = cand[i], b = cand[ixj];
                    bool desc = ((i & k) == 0);
                    if (desc ? (a < b) : (a > b)) { cand[i] = b; cand[ixj] = a; }
                }
            }
            __syncthreads();
        }
    }
    if (tid < TOPK) {
        unsigned long long kk = cand[tid];
        sel_score[c * TOPK + tid] = __uint_as_float((unsigned int)(kk >> 32));
        const int i = (int)(~(unsigned int)(kk & 0xFFFFFFFFull));
        // ---- inline decode + clip (bit-identical to previous decode_kernel)
        float x1 = proposals[i * 4 + 0], y1 = proposals[i * 4 + 1];
        float x2 = proposals[i * 4 + 2], y2 = proposals[i * 4 + 3];
        float w = x2 - x1 + 1.0f, h = y2 - y1 + 1.0f;
        float cx = x1 + 0.5f * w, cy = y1 + 0.5f * h;
        const float* d = box_reg + (size_t)i * (N_CLS * 4) + (size_t)(c + 1) * 4;
        float dx = d[0] / 10.0f, dy = d[1] / 10.0f;
        float dw = fminf(d[2] / 5.0f, BBOX_CLIP);
        float dh = fminf(d[3] / 5.0f, BBOX_CLIP);
        float pcx = dx * w + cx, pcy = dy * h + cy;
        float pw = expf(dw) * w, ph = expf(dh) * h;
        float ox1 = clampf(pcx - 0.5f * pw, 0.f, 1332.f);
        float oy1 = clampf(pcy - 0.5f * ph, 0.f, 799.f);
        float ox2 = clampf(pcx + 0.5f * pw - 1.0f, 0.f, 1332.f);
        float oy2 = clampf(pcy + 0.5f * ph - 1.0f, 0.f, 799.f);
        ((float4*)sel_box)[c * TOPK + tid] = make_float4(ox1, oy1, ox2, oy2);
    }
}

// ---------------------------------------------------------------------------
// Kernel 4a: suppression bitmask. Grid (class, 4 row-chunks, 4 j-tiles).
// Per-j areas precomputed into LDS (uniform-j broadcast read).
// ---------------------------------------------------------------------------
__global__ __launch_bounds__(256) void mask_kernel(
    const float* __restrict__ sel_box, unsigned long long* __restrict__ mask) {
#pragma clang fp contract(off)
    const int c = blockIdx.x;
    const int rbase = blockIdx.y * 256;
    const int jbase0 = blockIdx.z * 256;   // tile of 4 words
    const int r = rbase + threadIdx.x;
    unsigned long long* mrow = mask + ((size_t)c * TOPK + r) * NWORD;
    if (jbase0 + 255 <= rbase) {           // whole tile below diagonal
        if (r < TOPK) {
#pragma unroll
            for (int w4 = 0; w4 < 4; ++w4) mrow[blockIdx.z * 4 + w4] = 0ull;
        }
        return;
    }
    __shared__ float4 box[256];
    __shared__ float sarea[256];
    {
        int jload = jbase0 + threadIdx.x;
        if (jload < TOPK) {
            float4 b4 = ((const float4*)sel_box)[c * TOPK + jload];
            box[threadIdx.x] = b4;
            sarea[threadIdx.x] = (b4.z - b4.x + 1.0f) * (b4.w - b4.y + 1.0f);
        }
    }
    __syncthreads();
    if (r >= TOPK) return;
    const float4 br = ((const float4*)sel_box)[c * TOPK + r];
    const float ar = (br.z - br.x + 1.0f) * (br.w - br.y + 1.0f);
    for (int w4 = 0; w4 < 4; ++w4) {
        const int wglob = blockIdx.z * 4 + w4;
        const int jbase = wglob * 64;
        if (jbase + 63 <= r) { mrow[wglob] = 0ull; continue; }
        unsigned long long bits = 0ull;
        const int jend = (jbase + 64 < TOPK) ? jbase + 64 : TOPK;
        for (int j = jbase; j < jend; ++j) {
            float4 bj = box[j - jbase0];         // broadcast (uniform addr)
            float aj = sarea[j - jbase0];
            float ltx = fmaxf(br.x, bj.x), lty = fmaxf(br.y, bj.y);
            float rbx = fminf(br.z, bj.z), rby = fminf(br.w, bj.w);
            float iw = fmaxf(rbx - ltx + 1.0f, 0.f);
            float ih = fmaxf(rby - lty + 1.0f, 0.f);
            float inter = iw * ih;
            float uni = ar + aj - inter;
            float diff = (inter + inter) - uni;  // sign always exact
            bool sup;
            if (uni > 0.f && fabsf(diff) > uni * 5e-7f) {
                sup = diff > 0.f;                // fast path (taken ~always)
            } else {
                sup = (inter / uni) > 0.5f;      // exact-window fallback
            }
            if (sup && j > r) bits |= 1ull << (j - jbase);
        }
        mrow[wglob] = bits;
    }
}

// ---------------------------------------------------------------------------
// Kernel 4b: serial greedy sweep. 256 threads/class; 4 waves cooperatively
// stage the whole 128 KB mask into LDS (gfx950: 160 KB/WG), then wave 0
// runs the bit-exact boolean-algebra sweep entirely from LDS.
// Fused with final-topk fpos/fhist1.
// ---------------------------------------------------------------------------
__global__ __launch_bounds__(256) void nms_reduce_kernel(
    const unsigned long long* __restrict__ mask, float* __restrict__ sel_score,
    unsigned int* __restrict__ fpos, unsigned int* __restrict__ fhist1) {
    const int c = blockIdx.x;
    const int tid = threadIdx.x;
    const int lane = tid & 63;
    const int wv = tid >> 6;
    __shared__ __align__(16) unsigned long long smask[TOPK * NWORD]; // 125 KiB
    __shared__ unsigned long long keep_lds[NWORD];
    __shared__ unsigned int lh[1024];

    const unsigned long long* mbase = mask + (size_t)c * TOPK * NWORD;

    float sval[NWORD];
    unsigned long long keep = 0ull;
    if (wv == 0) {
        for (int wd = 0; wd < NWORD; ++wd) {
            int j = wd * 64 + lane;
            float s = (j < TOPK) ? sel_score[c * TOPK + j] : -1.0f;
            sval[wd] = s;
            unsigned long long m = __ballot(s > SCORE_THRESH);
            if ((lane & 15) == wd) keep = m;
        }
    }
    {
        ulonglong2* s2 = (ulonglong2*)smask;
        const ulonglong2* g2 = (const ulonglong2*)mbase;
        for (int i = tid; i < TOPK * NWORD / 2; i += 256) s2[i] = g2[i];
    }
    __syncthreads();

    if (wv == 0) {
        const int w = lane & 15;     // word index this lane owns
        const int d = lane >> 4;     // row-in-group slot 0..3
        const int NG = TOPK / 4;     // 250 groups
        unsigned long long p0 = smask[(size_t)(0 + d) * NWORD + w];
        unsigned long long p1 = smask[(size_t)(4 + d) * NWORD + w];
        for (int g = 0; g < NG; ++g) {
            unsigned long long cur = p0;
            p0 = p1;
            p1 = (g + 2 < NG) ? smask[(size_t)(4 * (g + 2) + d) * NWORD + w]
                              : 0ull;
            const int i0 = 4 * g;
            const int kwi = i0 >> 6;                // keep word for this group
            const unsigned int b = (unsigned)i0 & 63u;
            unsigned long long q0 = __shfl(cur, (0 << 4) | w);
            unsigned long long q1 = __shfl(cur, (1 << 4) | w);
            unsigned long long q2 = __shfl(cur, (2 << 4) | w);
            unsigned long long q3 = __shfl(cur, (3 << 4) | w);
            unsigned long long r0k = __shfl(cur, (0 << 4) | kwi);
            unsigned long long r1k = __shfl(cur, (1 << 4) | kwi);
            unsigned long long r2k = __shfl(cur, (2 << 4) | kwi);
            // serial dependency: ONE shuffle of keep per 4 rows
            unsigned long long kw = __shfl(keep, kwi);
            const unsigned int k01 = (unsigned)(kw >> b);
            const unsigned int r0s = (unsigned)(r0k >> b);
            const unsigned int r1s = (unsigned)(r1k >> b);
            const unsigned int r2s = (unsigned)(r2k >> b);
            const unsigned int a0 = k01 & 1u;
            const unsigned int a1 = (k01 >> 1) & ~(a0 & (r0s >> 1)) & 1u;
            const unsigned int a2 = (k01 >> 2) & ~(a0 & (r0s >> 2)) &
                                    ~(a1 & (r1s >> 2)) & 1u;
            const unsigned int a3 = (k01 >> 3) & ~(a0 & (r0s >> 3)) &
                                    ~(a1 & (r1s >> 3)) & ~(a2 & (r2s >> 3)) & 1u;
            keep &= ~((q0 & (0ull - (unsigned long long)a0)) |
                      (q1 & (0ull - (unsigned long long)a1)) |
                      (q2 & (0ull - (unsigned long long)a2)) |
                      (q3 & (0ull - (unsigned long long)a3)));
        }
        if (lane < NWORD) keep_lds[lane] = keep;   // d==0 replicas
    } else {
        for (int b = tid - 64; b < 1024; b += 192) lh[b] = 0u;
    }
    __syncthreads();

    if (wv == 0) {
        int mykept = 0;
        for (int ww = 0; ww < NWORD; ++ww) {
            if ((keep_lds[ww] >> lane) & 1ull) {
                unsigned int o = __float_as_uint(sval[ww]) | 0x80000000u;
                atomicAdd(&lh[o >> 22], 1u);
                ++mykept;
            }
        }
#pragma unroll
        for (int off = 32; off > 0; off >>= 1) mykept += __shfl_down(mykept, off);
        if (lane == 0 && mykept) atomicAdd(fpos, (unsigned int)mykept);
    }
    __syncthreads();

    for (int b = tid; b < 1024; b += 256)
        if (lh[b]) atomicAdd(&fhist1[b], lh[b]);
    for (int j = tid; j < TOPK; j += 256) {
        bool k = (keep_lds[j >> 6] >> (j & 63)) & 1ull;
        if (!k) sel_score[c * TOPK + j] = -1.0f;
    }
}

// ---------------------------------------------------------------------------
// Final top-100. Post-NMS values are exactly {score>0.05} U {-1}.
// ---------------------------------------------------------------------------
__global__ __launch_bounds__(256) void ftk_hist2_kernel(
    const float* __restrict__ sel_score, const unsigned int* __restrict__ fpos,
    const unsigned int* __restrict__ fhist1, unsigned int* __restrict__ fhist2) {
    const int tid = threadIdx.x;
    if (*fpos < DETS) return;
    __shared__ unsigned int sh[1024];
    __shared__ unsigned int s_b1;
#pragma unroll
    for (int q = 0; q < 4; ++q) sh[tid + q * 256] = fhist1[tid + q * 256];
    __syncthreads();
    suffix_scan_1024(sh, tid);
#pragma unroll
    for (int q = 0; q < 4; ++q) {
        int x = tid + q * 256;
        if (sh[x] >= DETS && (x == 1023 || sh[x + 1] < DETS)) s_b1 = (unsigned)x;
    }
    __syncthreads();
    const unsigned int b1 = s_b1;
    __syncthreads();
#pragma unroll
    for (int q = 0; q < 4; ++q) sh[tid + q * 256] = 0u;
    __syncthreads();
    const float* base = sel_score + blockIdx.x * TOPK;
    for (int i = tid; i < TOPK; i += 256) {
        float s = base[i];
        if (!(s > SCORE_THRESH)) continue;
        unsigned int o = __float_as_uint(s) | 0x80000000u;
        if ((o >> 22) == b1) atomicAdd(&sh[(o >> 12) & 1023u], 1u);
    }
    __syncthreads();
    for (int b = tid; b < 1024; b += 256)
        if (sh[b]) atomicAdd(&fhist2[b], sh[b]);
}

__global__ __launch_bounds__(256) void ftk_compact_kernel(
    const float* __restrict__ sel_score, const unsigned int* __restrict__ fpos,
    const unsigned int* __restrict__ fhist1, const unsigned int* __restrict__ fhist2,
    unsigned int* __restrict__ fcnt, unsigned long long* __restrict__ fcand) {
    const int tid = threadIdx.x;
    const unsigned int P = *fpos;
    __shared__ unsigned int sh[1024];
    __shared__ unsigned long long stage[1024];
    __shared__ unsigned int s_b1, s_above, s_b2, s_lcnt, s_base;
    if (tid == 0) s_lcnt = 0u;
    const float* base = sel_score + blockIdx.x * TOPK;
    const int fbase = blockIdx.x * TOPK;
    if (P >= DETS) {
#pragma unroll
        for (int q = 0; q < 4; ++q) sh[tid + q * 256] = fhist1[tid + q * 256];
        __syncthreads();
        suffix_scan_1024(sh, tid);
#pragma unroll
        for (int q = 0; q < 4; ++q) {
            int x = tid + q * 256;
            if (sh[x] >= DETS && (x == 1023 || sh[x + 1] < DETS)) {
                s_b1 = (unsigned)x;
                s_above = (x == 1023) ? 0u : sh[x + 1];
            }
        }
        __syncthreads();
        const unsigned int b1 = s_b1;
        const unsigned int need2 = DETS - s_above;
        __syncthreads();
#pragma unroll
        for (int q = 0; q < 4; ++q) sh[tid + q * 256] = fhist2[tid + q * 256];
        __syncthreads();
        suffix_scan_1024(sh, tid);
#pragma unroll
        for (int q = 0; q < 4; ++q) {
            int x = tid + q * 256;
            if (sh[x] >= need2 && (x == 1023 || sh[x + 1] < need2)) s_b2 = (unsigned)x;
        }
        __syncthreads();
        const unsigned int thresh20 = (s_b1 << 10) | s_b2;
        (void)b1;
        for (int i = tid; i < TOPK; i += 256) {
            float s = base[i];
            if (!(s > SCORE_THRESH)) continue;
            unsigned int o = __float_as_uint(s) | 0x80000000u;
            if ((o >> 12) >= thresh20) {
                unsigned int pos = atomicAdd(&s_lcnt, 1u);
                stage[pos] = ((unsigned long long)o << 32) |
                             (unsigned int)(~(unsigned int)(fbase + i));
            }
        }
    } else {
        for (int i = tid; i < TOPK; i += 256) {
            float s = base[i];
            int flat = fbase + i;
            if ((s > SCORE_THRESH) || flat < (int)(P + DETS)) {
                unsigned int u = __float_as_uint(s);
                unsigned int o = (u & 0x80000000u) ? ~u : (u | 0x80000000u);
                unsigned int pos = atomicAdd(&s_lcnt, 1u);
                stage[pos] = ((unsigned long long)o << 32) |
                             (unsigned int)(~(unsigned int)flat);
            }
        }
    }
    __syncthreads();
    unsigned int lcnt = s_lcnt < 1024u ? s_lcnt : 1024u;
    if (tid == 0) s_base = atomicAdd(fcnt, lcnt);  // ONE global atomic
    __syncthreads();
    const unsigned int bse = s_base;
    for (unsigned int i = tid; i < lcnt; i += 256) {
        unsigned int pos = bse + i;
        if (pos < CAND_MAX) fcand[pos] = stage[i];
    }
}

__global__ __launch_bounds__(1024) void ftk_sort_kernel(
    const unsigned long long* __restrict__ fcand,
    const unsigned int* __restrict__ fcnt,
    const float* __restrict__ sel_score, const float* __restrict__ sel_box,
    float* __restrict__ out) {
    const int tid = threadIdx.x;
    __shared__ unsigned long long cand[CAND_MAX];
    unsigned int cnt = *fcnt;
    if (cnt > CAND_MAX) cnt = CAND_MAX;
    const unsigned int n = (cnt <= 1024u) ? 1024u : (unsigned)CAND_MAX;
    for (unsigned int i = tid; i < n; i += 1024)
        cand[i] = (i < cnt) ? fcand[i] : 0ull;
    __syncthreads();
    for (unsigned int k = 2; k <= n; k <<= 1) {
        for (unsigned int j = k >> 1; j > 0; j >>= 1) {
            for (unsigned int i = tid; i < n; i += 1024) {
                unsigned int ixj = i ^ j;
                if (ixj > i) {
                    unsigned long long a = cand[i], b = cand[ixj];
                    bool desc = ((i & k) == 0);
                    if (desc ? (a < b) : (a > b)) { cand[i] = b; cand[ixj] = a; }
                }
            }
            __syncthreads();
        }
    }
    if (tid < DETS) {
        unsigned long long kk = cand[tid];
        unsigned int flat = ~(unsigned int)(kk & 0xFFFFFFFFull);
        float s = sel_score[flat];
        float4 b = ((const float4*)sel_box)[flat];
        out[tid * 4 + 0] = b.x;
        out[tid * 4 + 1] = b.y;
        out[tid * 4 + 2] = b.z;
        out[tid * 4 + 3] = b.w;
        out[400 + tid] = s;
        out[500 + tid] = (float)(flat / TOPK + 1);   // label
    }
}

// ---------------------------------------------------------------------------
extern "C" void kernel_launch(void* const* d_in, const int* in_sizes, int n_in,
                              void* d_out, int out_size, void* d_ws, size_t ws_size,
                              hipStream_t stream) {
    const float* logits    = (const float*)d_in[0];   // [100000, 91]
    const float* box_reg   = (const float*)d_in[1];   // [100000, 364]
    const float* proposals = (const float*)d_in[2];   // [100000, 4]
    float* out = (float*)d_out;                       // 600 floats

    char* ws = (char*)d_ws;
    size_t off = 0;
    auto walloc = [&](size_t bytes) -> char* {
        char* p = ws + off;
        off += (bytes + 255) & ~(size_t)255;
        return p;
    };
    float* scores_t = (float*)walloc((size_t)NFG * N_PROP * sizeof(float)); // 36 MB
    float* sel_score = (float*)walloc((size_t)NFG * TOPK * sizeof(float));
    float* sel_box   = (float*)walloc((size_t)NFG * TOPK * 4 * sizeof(float));
    // final-topk scratch (must survive mask writes -> own region)
    unsigned int* fscr = (unsigned int*)walloc((2 + 2048) * sizeof(unsigned int));
    unsigned int* fpos   = fscr;          // [1]
    unsigned int* fcnt   = fscr + 1;      // [1]
    unsigned int* fhist1 = fscr + 2;      // [1024]
    unsigned int* fhist2 = fscr + 2 + 1024; // [1024]
    unsigned long long* fcand =
        (unsigned long long*)walloc(CAND_MAX * sizeof(unsigned long long));
    unsigned long long* mask =
        (unsigned long long*)walloc((size_t)NFG * TOPK * NWORD * 8); // 11.5 MB
    // selection scratch UNIONED with mask region (last read by sortout_kernel,
    // which runs strictly before mask_kernel's first write)
    unsigned int* ghist1 = (unsigned int*)mask;                 // 90*1024
    unsigned int* ghist2 = ghist1 + NFG * 1024;                 // 90*1024
    unsigned int* gcnt   = ghist2 + NFG * 1024;                 // 90
    unsigned long long* gcand =
        (unsigned long long*)(((uintptr_t)(gcnt + NFG) + 255) & ~(uintptr_t)255);
    (void)ws_size; (void)in_sizes; (void)n_in; (void)out_size;

    const int nzero = NFG * 1024 * 2 + NFG;
    softmax_kernel<<<(N_PROP + 255) / 256, 256, 0, stream>>>(
        logits, scores_t, ghist1, nzero, fscr, 2 + 2048);
    hist1_kernel<<<dim3(NFG, CHUNKS), 256, 0, stream>>>(scores_t, ghist1);
    hist2_kernel<<<dim3(NFG, CHUNKS), 256, 0, stream>>>(scores_t, ghist1, ghist2);
    compact_kernel<<<dim3(NFG, CHUNKS), 256, 0, stream>>>(scores_t, ghist1, ghist2,
                                                          gcnt, gcand);
    sortout_kernel<<<NFG, 1024, 0, stream>>>(gcand, gcnt, box_reg, proposals,
                                             sel_score, sel_box);
    mask_kernel<<<dim3(NFG, 4, 4), 256, 0, stream>>>(sel_box, mask);
    nms_reduce_kernel<<<NFG, 256, 0, stream>>>(mask, sel_score, fpos, fhist1);
    ftk_hist2_kernel<<<NFG, 256, 0, stream>>>(sel_score, fpos, fhist1, fhist2);
    ftk_compact_kernel<<<NFG, 256, 0, stream>>>(sel_score, fpos, fhist1, fhist2,
                                                fcnt, fcand);
    ftk_sort_kernel<<<1, 1024, 0, stream>>>(fcand, fcnt, sel_score, sel_box, out);
}

// Round 7
// 457.956 us; speedup vs baseline: 1.1129x; 1.0224x over previous
//
#include <hip/hip_runtime.h>
#include <stdint.h>

#define N_PROP 100000
#define N_CLS  91
#define NFG    90          // foreground classes
#define TOPK   1000
#define NWORD  16          // 1000 bits -> 16 u64 words
#define CAND_MAX 2048
#define DETS   100
#define SCORE_THRESH 0.05f
#define BBOX_CLIP 4.135166556742356f   // log(1000/16)

__device__ __forceinline__ float clampf(float v, float lo, float hi) {
    return fminf(fmaxf(v, lo), hi);
}

// ---------------------------------------------------------------------------
// Kernel 1: softmax over 91 classes, write transposed scores_t[90][N_PROP].
// Also zeroes the final-topk scratch (fused, saves a launch).
// ---------------------------------------------------------------------------
__global__ __launch_bounds__(256) void softmax_kernel(
    const float* __restrict__ logits, float* __restrict__ scores_t,
    unsigned int* __restrict__ z1, int n1) {
    for (int i = blockIdx.x * 256 + threadIdx.x; i < n1; i += gridDim.x * 256)
        z1[i] = 0u;
    int row = blockIdx.x * blockDim.x + threadIdx.x;
    if (row >= N_PROP) return;
    const float* lrow = logits + (size_t)row * N_CLS;
    float m = -INFINITY;
    for (int c = 0; c < N_CLS; ++c) m = fmaxf(m, lrow[c]);
    float sum = 0.f;
    for (int c = 0; c < N_CLS; ++c) sum += expf(lrow[c] - m);
    for (int c = 1; c < N_CLS; ++c) {
        float s = expf(lrow[c] - m) / sum;
        scores_t[(size_t)(c - 1) * N_PROP + row] = s;  // coalesced per-c
    }
}

// 1024-thread suffix scan over 1024 bins (1 elem/thread)
__device__ __forceinline__ void suffix_scan_1024_t1k(unsigned int* sh, int tid) {
    for (int off = 1; off < 1024; off <<= 1) {
        unsigned int v = (tid + off < 1024) ? sh[tid + off] : 0u;
        __syncthreads();
        sh[tid] += v;
        __syncthreads();
    }
}

// 256-thread suffix scan over 1024 bins (4 elems/thread) — ftk kernels
__device__ __forceinline__ void suffix_scan_1024(unsigned int* sh, int tid) {
    for (int off = 1; off < 1024; off <<= 1) {
        unsigned int v[4];
#pragma unroll
        for (int q = 0; q < 4; ++q) {
            int x = tid + q * 256;
            v[q] = (x + off < 1024) ? sh[x + off] : 0u;
        }
        __syncthreads();
#pragma unroll
        for (int q = 0; q < 4; ++q) sh[tid + q * 256] += v[q];
        __syncthreads();
    }
}

// ---------------------------------------------------------------------------
// Kernel 2 (R7 fusion): per-class selection, ONE block per class.
// hist1 -> scan -> hist2 -> scan -> compact -> bitonic sort -> top-1000
// write + inline box decode. All radix/threshold/sort/decode logic is
// byte-identical to the proven chunked kernels; only the global hist/cand
// merge plumbing is removed (LDS-only hists, single-block class).
// Pass 2/3 re-reads of the 400 KB class slice hit L2.
// ---------------------------------------------------------------------------
__global__ __launch_bounds__(1024) void select_kernel(
    const float* __restrict__ scores_t,
    const float* __restrict__ box_reg, const float* __restrict__ proposals,
    float* __restrict__ sel_score, float* __restrict__ sel_box) {
#pragma clang fp contract(off)
    const int c = blockIdx.x, tid = threadIdx.x;
    __shared__ unsigned int lh[4][1024];               // 16 KB hist replicas
    __shared__ unsigned long long stage[CAND_MAX];     // 16 KB
    __shared__ unsigned int s_b1, s_above, s_b2, s_lcnt;
    unsigned int* sh = &lh[0][0];                      // scan buffer alias

    const float4* sc4 = (const float4*)(scores_t + (size_t)c * N_PROP);

    // ---- pass 1: hist1 on bits>>20 (scores in (0,1] -> bin < 1024) ----
    for (int i = tid; i < 4096; i += 1024) (&lh[0][0])[i] = 0u;
    __syncthreads();
    for (int i = tid; i < N_PROP / 4; i += 1024) {
        float4 v = sc4[i];
        atomicAdd(&lh[(tid + 0) & 3][__float_as_uint(v.x) >> 20], 1u);
        atomicAdd(&lh[(tid + 1) & 3][__float_as_uint(v.y) >> 20], 1u);
        atomicAdd(&lh[(tid + 2) & 3][__float_as_uint(v.z) >> 20], 1u);
        atomicAdd(&lh[(tid + 3) & 3][__float_as_uint(v.w) >> 20], 1u);
    }
    __syncthreads();
    sh[tid] = lh[0][tid] + lh[1][tid] + lh[2][tid] + lh[3][tid];
    __syncthreads();
    suffix_scan_1024_t1k(sh, tid);
    if (sh[tid] >= TOPK && (tid == 1023 || sh[tid + 1] < TOPK)) {
        s_b1 = (unsigned)tid;
        s_above = (tid == 1023) ? 0u : sh[tid + 1];
    }
    __syncthreads();
    const unsigned int b1 = s_b1;
    const unsigned int need2 = TOPK - s_above;
    __syncthreads();

    // ---- pass 2: hist2 on (bits>>10)&1023 within bucket b1 ----
    for (int i = tid; i < 4096; i += 1024) (&lh[0][0])[i] = 0u;
    __syncthreads();
    for (int i = tid; i < N_PROP / 4; i += 1024) {
        float4 v = sc4[i];
        unsigned int bx = __float_as_uint(v.x), by = __float_as_uint(v.y);
        unsigned int bz = __float_as_uint(v.z), bw = __float_as_uint(v.w);
        if ((bx >> 20) == b1) atomicAdd(&lh[(tid + 0) & 3][(bx >> 10) & 1023u], 1u);
        if ((by >> 20) == b1) atomicAdd(&lh[(tid + 1) & 3][(by >> 10) & 1023u], 1u);
        if ((bz >> 20) == b1) atomicAdd(&lh[(tid + 2) & 3][(bz >> 10) & 1023u], 1u);
        if ((bw >> 20) == b1) atomicAdd(&lh[(tid + 3) & 3][(bw >> 10) & 1023u], 1u);
    }
    __syncthreads();
    sh[tid] = lh[0][tid] + lh[1][tid] + lh[2][tid] + lh[3][tid];
    __syncthreads();
    suffix_scan_1024_t1k(sh, tid);
    if (sh[tid] >= need2 && (tid == 1023 || sh[tid + 1] < need2))
        s_b2 = (unsigned)tid;
    if (tid == 0) s_lcnt = 0u;
    __syncthreads();
    const unsigned int thresh22 = (b1 << 10) | s_b2;
    __syncthreads();

    // ---- pass 3: compact candidates into LDS stage ----
    for (int i = tid; i < N_PROP / 4; i += 1024) {
        float4 v = sc4[i];
#pragma unroll
        for (int k = 0; k < 4; ++k) {
            unsigned int bits = __float_as_uint(k == 0 ? v.x : k == 1 ? v.y
                                                : k == 2 ? v.z : v.w);
            if ((bits >> 10) >= thresh22) {
                unsigned int pos = atomicAdd(&s_lcnt, 1u);
                if (pos < CAND_MAX)
                    stage[pos] = ((unsigned long long)bits << 32) |
                                 (unsigned int)(~(unsigned int)(4 * i + k));
            }
        }
    }
    __syncthreads();
    const unsigned int lcnt = s_lcnt < CAND_MAX ? s_lcnt : CAND_MAX;
    const unsigned int n = (lcnt <= 1024u) ? 1024u : (unsigned)CAND_MAX;
    for (unsigned int i = tid; i < n; i += 1024)
        if (i >= lcnt) stage[i] = 0ull;
    __syncthreads();

    // ---- bitonic sort (desc) ----
    for (unsigned int k = 2; k <= n; k <<= 1) {
        for (unsigned int j = k >> 1; j > 0; j >>= 1) {
            for (unsigned int i = tid; i < n; i += 1024) {
                unsigned int ixj = i ^ j;
                if (ixj > i) {
                    unsigned long long a = stage[i], b = stage[ixj];
                    bool desc = ((i & k) == 0);
                    if (desc ? (a < b) : (a > b)) { stage[i] = b; stage[ixj] = a; }
                }
            }
            __syncthreads();
        }
    }

    // ---- top-1000 write + inline decode (identical to old sortout tail) ----
    if (tid < TOPK) {
        unsigned long long kk = stage[tid];
        sel_score[c * TOPK + tid] = __uint_as_float((unsigned int)(kk >> 32));
        const int i = (int)(~(unsigned int)(kk & 0xFFFFFFFFull));
        float x1 = proposals[i * 4 + 0], y1 = proposals[i * 4 + 1];
        float x2 = proposals[i * 4 + 2], y2 = proposals[i * 4 + 3];
        float w = x2 - x1 + 1.0f, h = y2 - y1 + 1.0f;
        float cx = x1 + 0.5f * w, cy = y1 + 0.5f * h;
        const float* d = box_reg + (size_t)i * (N_CLS * 4) + (size_t)(c + 1) * 4;
        float dx = d[0] / 10.0f, dy = d[1] / 10.0f;
        float dw = fminf(d[2] / 5.0f, BBOX_CLIP);
        float dh = fminf(d[3] / 5.0f, BBOX_CLIP);
        float pcx = dx * w + cx, pcy = dy * h + cy;
        float pw = expf(dw) * w, ph = expf(dh) * h;
        float ox1 = clampf(pcx - 0.5f * pw, 0.f, 1332.f);
        float oy1 = clampf(pcy - 0.5f * ph, 0.f, 799.f);
        float ox2 = clampf(pcx + 0.5f * pw - 1.0f, 0.f, 1332.f);
        float oy2 = clampf(pcy + 0.5f * ph - 1.0f, 0.f, 799.f);
        ((float4*)sel_box)[c * TOPK + tid] = make_float4(ox1, oy1, ox2, oy2);
    }
}

// ---------------------------------------------------------------------------
// Kernel 3: suppression bitmask. Grid (class, 4 row-chunks, 4 j-tiles).
// ---------------------------------------------------------------------------
__global__ __launch_bounds__(256) void mask_kernel(
    const float* __restrict__ sel_box, unsigned long long* __restrict__ mask) {
#pragma clang fp contract(off)
    const int c = blockIdx.x;
    const int rbase = blockIdx.y * 256;
    const int jbase0 = blockIdx.z * 256;   // tile of 4 words
    const int r = rbase + threadIdx.x;
    unsigned long long* mrow = mask + ((size_t)c * TOPK + r) * NWORD;
    if (jbase0 + 255 <= rbase) {           // whole tile below diagonal
        if (r < TOPK) {
#pragma unroll
            for (int w4 = 0; w4 < 4; ++w4) mrow[blockIdx.z * 4 + w4] = 0ull;
        }
        return;
    }
    __shared__ float4 box[256];
    __shared__ float sarea[256];
    {
        int jload = jbase0 + threadIdx.x;
        if (jload < TOPK) {
            float4 b4 = ((const float4*)sel_box)[c * TOPK + jload];
            box[threadIdx.x] = b4;
            sarea[threadIdx.x] = (b4.z - b4.x + 1.0f) * (b4.w - b4.y + 1.0f);
        }
    }
    __syncthreads();
    if (r >= TOPK) return;
    const float4 br = ((const float4*)sel_box)[c * TOPK + r];
    const float ar = (br.z - br.x + 1.0f) * (br.w - br.y + 1.0f);
    for (int w4 = 0; w4 < 4; ++w4) {
        const int wglob = blockIdx.z * 4 + w4;
        const int jbase = wglob * 64;
        if (jbase + 63 <= r) { mrow[wglob] = 0ull; continue; }
        unsigned long long bits = 0ull;
        const int jend = (jbase + 64 < TOPK) ? jbase + 64 : TOPK;
        for (int j = jbase; j < jend; ++j) {
            float4 bj = box[j - jbase0];         // broadcast (uniform addr)
            float aj = sarea[j - jbase0];
            float ltx = fmaxf(br.x, bj.x), lty = fmaxf(br.y, bj.y);
            float rbx = fminf(br.z, bj.z), rby = fminf(br.w, bj.w);
            float iw = fmaxf(rbx - ltx + 1.0f, 0.f);
            float ih = fmaxf(rby - lty + 1.0f, 0.f);
            float inter = iw * ih;
            float uni = ar + aj - inter;
            float diff = (inter + inter) - uni;  // sign always exact
            bool sup;
            if (uni > 0.f && fabsf(diff) > uni * 5e-7f) {
                sup = diff > 0.f;                // fast path (taken ~always)
            } else {
                sup = (inter / uni) > 0.5f;      // exact-window fallback
            }
            if (sup && j > r) bits |= 1ull << (j - jbase);
        }
        mrow[wglob] = bits;
    }
}

// ---------------------------------------------------------------------------
// Kernel 4: serial greedy sweep. 256 threads/class; 4 waves cooperatively
// stage the whole 128 KB mask into LDS, wave 0 runs the bit-exact
// boolean-algebra sweep from LDS. Fused with final-topk fpos/fhist1.
// ---------------------------------------------------------------------------
__global__ __launch_bounds__(256) void nms_reduce_kernel(
    const unsigned long long* __restrict__ mask, float* __restrict__ sel_score,
    unsigned int* __restrict__ fpos, unsigned int* __restrict__ fhist1) {
    const int c = blockIdx.x;
    const int tid = threadIdx.x;
    const int lane = tid & 63;
    const int wv = tid >> 6;
    __shared__ __align__(16) unsigned long long smask[TOPK * NWORD]; // 125 KiB
    __shared__ unsigned long long keep_lds[NWORD];
    __shared__ unsigned int lh[1024];

    const unsigned long long* mbase = mask + (size_t)c * TOPK * NWORD;

    float sval[NWORD];
    unsigned long long keep = 0ull;
    if (wv == 0) {
        for (int wd = 0; wd < NWORD; ++wd) {
            int j = wd * 64 + lane;
            float s = (j < TOPK) ? sel_score[c * TOPK + j] : -1.0f;
            sval[wd] = s;
            unsigned long long m = __ballot(s > SCORE_THRESH);
            if ((lane & 15) == wd) keep = m;
        }
    }
    {
        ulonglong2* s2 = (ulonglong2*)smask;
        const ulonglong2* g2 = (const ulonglong2*)mbase;
        for (int i = tid; i < TOPK * NWORD / 2; i += 256) s2[i] = g2[i];
    }
    __syncthreads();

    if (wv == 0) {
        const int w = lane & 15;     // word index this lane owns
        const int d = lane >> 4;     // row-in-group slot 0..3
        const int NG = TOPK / 4;     // 250 groups
        unsigned long long p0 = smask[(size_t)(0 + d) * NWORD + w];
        unsigned long long p1 = smask[(size_t)(4 + d) * NWORD + w];
        for (int g = 0; g < NG; ++g) {
            unsigned long long cur = p0;
            p0 = p1;
            p1 = (g + 2 < NG) ? smask[(size_t)(4 * (g + 2) + d) * NWORD + w]
                              : 0ull;
            const int i0 = 4 * g;
            const int kwi = i0 >> 6;                // keep word for this group
            const unsigned int b = (unsigned)i0 & 63u;
            unsigned long long q0 = __shfl(cur, (0 << 4) | w);
            unsigned long long q1 = __shfl(cur, (1 << 4) | w);
            unsigned long long q2 = __shfl(cur, (2 << 4) | w);
            unsigned long long q3 = __shfl(cur, (3 << 4) | w);
            unsigned long long r0k = __shfl(cur, (0 << 4) | kwi);
            unsigned long long r1k = __shfl(cur, (1 << 4) | kwi);
            unsigned long long r2k = __shfl(cur, (2 << 4) | kwi);
            // serial dependency: ONE shuffle of keep per 4 rows
            unsigned long long kw = __shfl(keep, kwi);
            const unsigned int k01 = (unsigned)(kw >> b);
            const unsigned int r0s = (unsigned)(r0k >> b);
            const unsigned int r1s = (unsigned)(r1k >> b);
            const unsigned int r2s = (unsigned)(r2k >> b);
            const unsigned int a0 = k01 & 1u;
            const unsigned int a1 = (k01 >> 1) & ~(a0 & (r0s >> 1)) & 1u;
            const unsigned int a2 = (k01 >> 2) & ~(a0 & (r0s >> 2)) &
                                    ~(a1 & (r1s >> 2)) & 1u;
            const unsigned int a3 = (k01 >> 3) & ~(a0 & (r0s >> 3)) &
                                    ~(a1 & (r1s >> 3)) & ~(a2 & (r2s >> 3)) & 1u;
            keep &= ~((q0 & (0ull - (unsigned long long)a0)) |
                      (q1 & (0ull - (unsigned long long)a1)) |
                      (q2 & (0ull - (unsigned long long)a2)) |
                      (q3 & (0ull - (unsigned long long)a3)));
        }
        if (lane < NWORD) keep_lds[lane] = keep;   // d==0 replicas
    } else {
        for (int b = tid - 64; b < 1024; b += 192) lh[b] = 0u;
    }
    __syncthreads();

    if (wv == 0) {
        int mykept = 0;
        for (int ww = 0; ww < NWORD; ++ww) {
            if ((keep_lds[ww] >> lane) & 1ull) {
                unsigned int o = __float_as_uint(sval[ww]) | 0x80000000u;
                atomicAdd(&lh[o >> 22], 1u);
                ++mykept;
            }
        }
#pragma unroll
        for (int off = 32; off > 0; off >>= 1) mykept += __shfl_down(mykept, off);
        if (lane == 0 && mykept) atomicAdd(fpos, (unsigned int)mykept);
    }
    __syncthreads();

    for (int b = tid; b < 1024; b += 256)
        if (lh[b]) atomicAdd(&fhist1[b], lh[b]);
    for (int j = tid; j < TOPK; j += 256) {
        bool k = (keep_lds[j >> 6] >> (j & 63)) & 1ull;
        if (!k) sel_score[c * TOPK + j] = -1.0f;
    }
}

// ---------------------------------------------------------------------------
// Final top-100. Post-NMS values are exactly {score>0.05} U {-1}.
// ---------------------------------------------------------------------------
__global__ __launch_bounds__(256) void ftk_hist2_kernel(
    const float* __restrict__ sel_score, const unsigned int* __restrict__ fpos,
    const unsigned int* __restrict__ fhist1, unsigned int* __restrict__ fhist2) {
    const int tid = threadIdx.x;
    if (*fpos < DETS) return;
    __shared__ unsigned int sh[1024];
    __shared__ unsigned int s_b1;
#pragma unroll
    for (int q = 0; q < 4; ++q) sh[tid + q * 256] = fhist1[tid + q * 256];
    __syncthreads();
    suffix_scan_1024(sh, tid);
#pragma unroll
    for (int q = 0; q < 4; ++q) {
        int x = tid + q * 256;
        if (sh[x] >= DETS && (x == 1023 || sh[x + 1] < DETS)) s_b1 = (unsigned)x;
    }
    __syncthreads();
    const unsigned int b1 = s_b1;
    __syncthreads();
#pragma unroll
    for (int q = 0; q < 4; ++q) sh[tid + q * 256] = 0u;
    __syncthreads();
    const float* base = sel_score + blockIdx.x * TOPK;
    for (int i = tid; i < TOPK; i += 256) {
        float s = base[i];
        if (!(s > SCORE_THRESH)) continue;
        unsigned int o = __float_as_uint(s) | 0x80000000u;
        if ((o >> 22) == b1) atomicAdd(&sh[(o >> 12) & 1023u], 1u);
    }
    __syncthreads();
    for (int b = tid; b < 1024; b += 256)
        if (sh[b]) atomicAdd(&fhist2[b], sh[b]);
}

__global__ __launch_bounds__(256) void ftk_compact_kernel(
    const float* __restrict__ sel_score, const unsigned int* __restrict__ fpos,
    const unsigned int* __restrict__ fhist1, const unsigned int* __restrict__ fhist2,
    unsigned int* __restrict__ fcnt, unsigned long long* __restrict__ fcand) {
    const int tid = threadIdx.x;
    const unsigned int P = *fpos;
    __shared__ unsigned int sh[1024];
    __shared__ unsigned long long stage[1024];
    __shared__ unsigned int s_b1, s_above, s_b2, s_lcnt, s_base;
    if (tid == 0) s_lcnt = 0u;
    const float* base = sel_score + blockIdx.x * TOPK;
    const int fbase = blockIdx.x * TOPK;
    if (P >= DETS) {
#pragma unroll
        for (int q = 0; q < 4; ++q) sh[tid + q * 256] = fhist1[tid + q * 256];
        __syncthreads();
        suffix_scan_1024(sh, tid);
#pragma unroll
        for (int q = 0; q < 4; ++q) {
            int x = tid + q * 256;
            if (sh[x] >= DETS && (x == 1023 || sh[x + 1] < DETS)) {
                s_b1 = (unsigned)x;
                s_above = (x == 1023) ? 0u : sh[x + 1];
            }
        }
        __syncthreads();
        const unsigned int b1 = s_b1;
        const unsigned int need2 = DETS - s_above;
        __syncthreads();
#pragma unroll
        for (int q = 0; q < 4; ++q) sh[tid + q * 256] = fhist2[tid + q * 256];
        __syncthreads();
        suffix_scan_1024(sh, tid);
#pragma unroll
        for (int q = 0; q < 4; ++q) {
            int x = tid + q * 256;
            if (sh[x] >= need2 && (x == 1023 || sh[x + 1] < need2)) s_b2 = (unsigned)x;
        }
        __syncthreads();
        const unsigned int thresh20 = (s_b1 << 10) | s_b2;
        (void)b1;
        for (int i = tid; i < TOPK; i += 256) {
            float s = base[i];
            if (!(s > SCORE_THRESH)) continue;
            unsigned int o = __float_as_uint(s) | 0x80000000u;
            if ((o >> 12) >= thresh20) {
                unsigned int pos = atomicAdd(&s_lcnt, 1u);
                stage[pos] = ((unsigned long long)o << 32) |
                             (unsigned int)(~(unsigned int)(fbase + i));
            }
        }
    } else {
        for (int i = tid; i < TOPK; i += 256) {
            float s = base[i];
            int flat = fbase + i;
            if ((s > SCORE_THRESH) || flat < (int)(P + DETS)) {
                unsigned int u = __float_as_uint(s);
                unsigned int o = (u & 0x80000000u) ? ~u : (u | 0x80000000u);
                unsigned int pos = atomicAdd(&s_lcnt, 1u);
                stage[pos] = ((unsigned long long)o << 32) |
                             (unsigned int)(~(unsigned int)flat);
            }
        }
    }
    __syncthreads();
    unsigned int lcnt = s_lcnt < 1024u ? s_lcnt : 1024u;
    if (tid == 0) s_base = atomicAdd(fcnt, lcnt);  // ONE global atomic
    __syncthreads();
    const unsigned int bse = s_base;
    for (unsigned int i = tid; i < lcnt; i += 256) {
        unsigned int pos = bse + i;
        if (pos < CAND_MAX) fcand[pos] = stage[i];
    }
}

__global__ __launch_bounds__(1024) void ftk_sort_kernel(
    const unsigned long long* __restrict__ fcand,
    const unsigned int* __restrict__ fcnt,
    const float* __restrict__ sel_score, const float* __restrict__ sel_box,
    float* __restrict__ out) {
    const int tid = threadIdx.x;
    __shared__ unsigned long long cand[CAND_MAX];
    unsigned int cnt = *fcnt;
    if (cnt > CAND_MAX) cnt = CAND_MAX;
    const unsigned int n = (cnt <= 1024u) ? 1024u : (unsigned)CAND_MAX;
    for (unsigned int i = tid; i < n; i += 1024)
        cand[i] = (i < cnt) ? fcand[i] : 0ull;
    __syncthreads();
    for (unsigned int k = 2; k <= n; k <<= 1) {
        for (unsigned int j = k >> 1; j > 0; j >>= 1) {
            for (unsigned int i = tid; i < n; i += 1024) {
                unsigned int ixj = i ^ j;
                if (ixj > i) {
                    unsigned long long a = cand[i], b = cand[ixj];
                    bool desc = ((i & k) == 0);
                    if (desc ? (a < b) : (a > b)) { cand[i] = b; cand[ixj] = a; }
                }
            }
            __syncthreads();
        }
    }
    if (tid < DETS) {
        unsigned long long kk = cand[tid];
        unsigned int flat = ~(unsigned int)(kk & 0xFFFFFFFFull);
        float s = sel_score[flat];
        float4 b = ((const float4*)sel_box)[flat];
        out[tid * 4 + 0] = b.x;
        out[tid * 4 + 1] = b.y;
        out[tid * 4 + 2] = b.z;
        out[tid * 4 + 3] = b.w;
        out[400 + tid] = s;
        out[500 + tid] = (float)(flat / TOPK + 1);   // label
    }
}

// ---------------------------------------------------------------------------
extern "C" void kernel_launch(void* const* d_in, const int* in_sizes, int n_in,
                              void* d_out, int out_size, void* d_ws, size_t ws_size,
                              hipStream_t stream) {
    const float* logits    = (const float*)d_in[0];   // [100000, 91]
    const float* box_reg   = (const float*)d_in[1];   // [100000, 364]
    const float* proposals = (const float*)d_in[2];   // [100000, 4]
    float* out = (float*)d_out;                       // 600 floats

    char* ws = (char*)d_ws;
    size_t off = 0;
    auto walloc = [&](size_t bytes) -> char* {
        char* p = ws + off;
        off += (bytes + 255) & ~(size_t)255;
        return p;
    };
    float* scores_t = (float*)walloc((size_t)NFG * N_PROP * sizeof(float)); // 36 MB
    float* sel_score = (float*)walloc((size_t)NFG * TOPK * sizeof(float));
    float* sel_box   = (float*)walloc((size_t)NFG * TOPK * 4 * sizeof(float));
    // final-topk scratch
    unsigned int* fscr = (unsigned int*)walloc((2 + 2048) * sizeof(unsigned int));
    unsigned int* fpos   = fscr;          // [1]
    unsigned int* fcnt   = fscr + 1;      // [1]
    unsigned int* fhist1 = fscr + 2;      // [1024]
    unsigned int* fhist2 = fscr + 2 + 1024; // [1024]
    unsigned long long* fcand =
        (unsigned long long*)walloc(CAND_MAX * sizeof(unsigned long long));
    unsigned long long* mask =
        (unsigned long long*)walloc((size_t)NFG * TOPK * NWORD * 8); // 11.5 MB
    (void)ws_size; (void)in_sizes; (void)n_in; (void)out_size;

    softmax_kernel<<<(N_PROP + 255) / 256, 256, 0, stream>>>(
        logits, scores_t, fscr, 2 + 2048);
    select_kernel<<<NFG, 1024, 0, stream>>>(scores_t, box_reg, proposals,
                                            sel_score, sel_box);
    mask_kernel<<<dim3(NFG, 4, 4), 256, 0, stream>>>(sel_box, mask);
    nms_reduce_kernel<<<NFG, 256, 0, stream>>>(mask, sel_score, fpos, fhist1);
    ftk_hist2_kernel<<<NFG, 256, 0, stream>>>(sel_score, fpos, fhist1, fhist2);
    ftk_compact_kernel<<<NFG, 256, 0, stream>>>(sel_score, fpos, fhist1, fhist2,
                                                fcnt, fcand);
    ftk_sort_kernel<<<1, 1024, 0, stream>>>(fcand, fcnt, sel_score, sel_box, out);
}